// Round 15
// baseline (5424.159 us; speedup 1.0000x reference)
//
#include <hip/hip_runtime.h>
#include <math.h>

// ---------------------------------------------------------------------------
// 3-layer GCN on MI355X, fused aggregate-then-GEMM form.
//   out = relu( (A_hat @ in) @ W + b ),  A_hat = D^-1/2 (A+I) D^-1/2
// bf16 prescaled gather rows (s = bf16(dinv*h), 256B/row), 8B/lane, two
// 32-lane halves fetch TWO edges per VMEM instruction (128B quarter-wave
// requests -> exact bytes at depth 4; depth >=12 amplifies FETCH ~2.5x).
// Round-15: __launch_bounds__(512, 4). Evidence (r12/r14): the 2nd arg acts
// like CUDA min-BLOCKS-per-CU; (512,8) implied 64 waves/CU -> VGPR=32 ->
// 3x spill traffic. (512,4) = 32 waves/CU -> VGPR cap 64 (>= ~40 live regs,
// no spill) with W packed bf16 in LDS (32KB -> 4 blocks/CU by LDS).
// Occupancy ~90% lifts random-gather rate 1.15 -> ~2.2-2.5 TB/s (r12/r14:
// 90+% occupancy sustained 2.15-2.5 TB/s even while spilling).
// CSR over dst rebuilt on-device every call.
// ---------------------------------------------------------------------------

__device__ __forceinline__ unsigned short f2bf(float f) {
  unsigned u = __float_as_uint(f);
  return (unsigned short)((u + 0x7FFFu + ((u >> 16) & 1u)) >> 16);
}
__device__ __forceinline__ float bfLo(unsigned v) { return __uint_as_float(v << 16); }
__device__ __forceinline__ float bfHi(unsigned v) { return __uint_as_float(v & 0xFFFF0000u); }

// ------------------------------- CSR build ---------------------------------

__global__ __launch_bounds__(256) void k_zero(int* __restrict__ cnt,
                                              int* __restrict__ fillPos, int n) {
  int i = blockIdx.x * blockDim.x + threadIdx.x;
  if (i < n) { cnt[i] = 0; fillPos[i] = 0; }
}

__global__ __launch_bounds__(256) void k_deg(const int* __restrict__ dst,
                                             int* __restrict__ cnt, int E) {
  int i = blockIdx.x * blockDim.x + threadIdx.x;
  int stride = gridDim.x * blockDim.x;
  for (; i < E; i += stride) atomicAdd(&cnt[dst[i]], 1);
}

__global__ __launch_bounds__(256) void k_dinv(const int* __restrict__ cnt,
                                              float* __restrict__ dinv, int n) {
  int i = blockIdx.x * blockDim.x + threadIdx.x;
  if (i < n) dinv[i] = rsqrtf(1.0f + (float)cnt[i]);
}

__global__ __launch_bounds__(256) void k_scan1(const int* __restrict__ cnt,
                                               int* __restrict__ exc,
                                               int* __restrict__ bsum, int n) {
  __shared__ int lds[256];
  int t = threadIdx.x;
  int base = blockIdx.x * 1024 + t * 4;
  int v0 = (base + 0 < n) ? cnt[base + 0] : 0;
  int v1 = (base + 1 < n) ? cnt[base + 1] : 0;
  int v2 = (base + 2 < n) ? cnt[base + 2] : 0;
  int v3 = (base + 3 < n) ? cnt[base + 3] : 0;
  int sum = v0 + v1 + v2 + v3;
  lds[t] = sum;
  __syncthreads();
  for (int off = 1; off < 256; off <<= 1) {
    int val = lds[t];
    if (t >= off) val += lds[t - off];
    __syncthreads();
    lds[t] = val;
    __syncthreads();
  }
  int ex = lds[t] - sum;
  if (base + 0 < n) exc[base + 0] = ex;
  ex += v0;
  if (base + 1 < n) exc[base + 1] = ex;
  ex += v1;
  if (base + 2 < n) exc[base + 2] = ex;
  ex += v2;
  if (base + 3 < n) exc[base + 3] = ex;
  if (t == 255) bsum[blockIdx.x] = lds[255];
}

__global__ __launch_bounds__(128) void k_scan2(int* __restrict__ bsum, int nb) {
  __shared__ int lds[128];
  int t = threadIdx.x;
  int v = (t < nb) ? bsum[t] : 0;
  lds[t] = v;
  __syncthreads();
  for (int off = 1; off < 128; off <<= 1) {
    int val = lds[t];
    if (t >= off) val += lds[t - off];
    __syncthreads();
    lds[t] = val;
    __syncthreads();
  }
  if (t < nb) bsum[t] = lds[t] - v;
}

__global__ __launch_bounds__(256) void k_scan3(int* __restrict__ exc,
                                               const int* __restrict__ bsum, int n) {
  int i = blockIdx.x * blockDim.x + threadIdx.x;
  if (i < n) exc[i] += bsum[i >> 10];
}

__global__ __launch_bounds__(256) void k_fill(const int* __restrict__ src,
                                              const int* __restrict__ dst,
                                              const int* __restrict__ rowStart,
                                              int* __restrict__ fillPos,
                                              int* __restrict__ eSrc, int E) {
  int i = blockIdx.x * blockDim.x + threadIdx.x;
  int stride = gridDim.x * blockDim.x;
  for (; i < E; i += stride) {
    int d = dst[i];
    int p = rowStart[d] + atomicAdd(&fillPos[d], 1);
    eSrc[p] = src[i];
  }
}

// ---------------- bf16 prescale: s = bf16(dinv * h), 256B rows -------------

__global__ __launch_bounds__(256) void k_scale(const float* __restrict__ h,
                                               const float* __restrict__ dinv,
                                               uint4* __restrict__ s4, int nQuads) {
  int i = blockIdx.x * blockDim.x + threadIdx.x;
  int stride = gridDim.x * blockDim.x;
  for (; i < nQuads; i += stride) {
    int row = i >> 4;
    int q = i & 15;
    float dv = dinv[row];
    const float4* hp = (const float4*)&h[(size_t)row * 128 + 8 * q];
    float4 a = hp[0], b = hp[1];
    uint4 o;
    o.x = (unsigned)f2bf(dv * a.x) | ((unsigned)f2bf(dv * a.y) << 16);
    o.y = (unsigned)f2bf(dv * a.z) | ((unsigned)f2bf(dv * a.w) << 16);
    o.z = (unsigned)f2bf(dv * b.x) | ((unsigned)f2bf(dv * b.y) << 16);
    o.w = (unsigned)f2bf(dv * b.z) | ((unsigned)f2bf(dv * b.w) << 16);
    s4[i] = o;
  }
}

// ---- fused layer: bf2 depth-4 gather, W packed bf16 in LDS, 32 waves/CU ---
// Lane l: half = l>>5, sl = l&31; lane owns bf16 cols 4*sl..4*sl+3 of s.
// Pair step: half 0 gathers edge A's 256B row, half 1 edge B's (uint2/lane).
// W in LDS as bf16 pairs: Wlb[k*(NFO/2)+cp] = pack(W[k][2cp], W[k][2cp+1]).
template <int NFO, bool RELU>
__global__ __launch_bounds__(512, 4) void k_layer_bf7(const unsigned* __restrict__ sU,
                                                      const float* __restrict__ W,
                                                      const float* __restrict__ bias,
                                                      const float* __restrict__ dinv,
                                                      const int* __restrict__ eSrc,
                                                      const int* __restrict__ rowStart,
                                                      const int* __restrict__ cnt,
                                                      float* __restrict__ out, int n) {
  __shared__ unsigned Wlb[64 * NFO];  // 128 rows x NFO/2 packed pairs
  for (int t = threadIdx.x; t < 64 * NFO; t += 512) {
    float2 w2 = *(const float2*)&W[2 * t];  // pairs contiguous in row-major W
    Wlb[t] = (unsigned)f2bf(w2.x) | ((unsigned)f2bf(w2.y) << 16);
  }
  __syncthreads();
  const int wid = threadIdx.x >> 6, lane = threadIdx.x & 63;
  const int half = lane >> 5, sl = lane & 31;
  for (int node = blockIdx.x * 8 + wid; node < n; node += gridDim.x * 8) {
    const int st = rowStart[node], c = cnt[node];
    const int* es = eSrc + st;
    const float dv = dinv[node];
    uint2 vs = *(const uint2*)&sU[(size_t)node * 64 + 2 * sl];  // self row
    float a0, a1, a2, a3;
    if (half == 0) {
      a0 = bfLo(vs.x); a1 = bfHi(vs.x); a2 = bfLo(vs.y); a3 = bfHi(vs.y);
    } else {
      a0 = a1 = a2 = a3 = 0.f;
    }
    const int cl = c < 64 ? c : 64;
    int myIdx = (lane < cl) ? es[lane] : 0;
    int j = 0;
    for (; j + 8 <= cl; j += 8) {  // 4 independent pair-loads = 8 edges
      int iA0 = __shfl(myIdx, j + 0), iB0 = __shfl(myIdx, j + 1);
      int iA1 = __shfl(myIdx, j + 2), iB1 = __shfl(myIdx, j + 3);
      int iA2 = __shfl(myIdx, j + 4), iB2 = __shfl(myIdx, j + 5);
      int iA3 = __shfl(myIdx, j + 6), iB3 = __shfl(myIdx, j + 7);
      int x0 = half ? iB0 : iA0;
      int x1 = half ? iB1 : iA1;
      int x2 = half ? iB2 : iA2;
      int x3 = half ? iB3 : iA3;
      uint2 v0 = *(const uint2*)&sU[(size_t)x0 * 64 + 2 * sl];
      uint2 v1 = *(const uint2*)&sU[(size_t)x1 * 64 + 2 * sl];
      uint2 v2 = *(const uint2*)&sU[(size_t)x2 * 64 + 2 * sl];
      uint2 v3 = *(const uint2*)&sU[(size_t)x3 * 64 + 2 * sl];
      a0 += bfLo(v0.x); a1 += bfHi(v0.x); a2 += bfLo(v0.y); a3 += bfHi(v0.y);
      a0 += bfLo(v1.x); a1 += bfHi(v1.x); a2 += bfLo(v1.y); a3 += bfHi(v1.y);
      a0 += bfLo(v2.x); a1 += bfHi(v2.x); a2 += bfLo(v2.y); a3 += bfHi(v2.y);
      a0 += bfLo(v3.x); a1 += bfHi(v3.x); a2 += bfLo(v3.y); a3 += bfHi(v3.y);
    }
    for (; j < c; j += 2) {  // pair tail (odd c and c>64)
      int iA = (j < cl) ? __shfl(myIdx, j) : es[j];
      int hasB = (j + 1 < c);
      int iB = hasB ? ((j + 1 < cl) ? __shfl(myIdx, j + 1) : es[j + 1]) : iA;
      int x = half ? iB : iA;
      uint2 v = *(const uint2*)&sU[(size_t)x * 64 + 2 * sl];
      if (half && !hasB) { v.x = 0u; v.y = 0u; }
      a0 += bfLo(v.x); a1 += bfHi(v.x); a2 += bfLo(v.y); a3 += bfHi(v.y);
    }
    a0 += __shfl_xor(a0, 32);
    a1 += __shfl_xor(a1, 32);
    a2 += __shfl_xor(a2, 32);
    a3 += __shfl_xor(a3, 32);
    a0 *= dv; a1 *= dv; a2 *= dv; a3 *= dv;  // t[4*sl + r]
    // row-GEMM: out_col = sum_k t[k]*W[k][col]; t[4q+r] read from lane q
    if constexpr (NFO == 128) {
      float o0 = 0.f, o1 = 0.f;
      #pragma unroll
      for (int q = 0; q < 32; q++) {
        float t0 = __shfl(a0, q);
        float t1 = __shfl(a1, q);
        float t2 = __shfl(a2, q);
        float t3 = __shfl(a3, q);
        unsigned w0 = Wlb[(4 * q + 0) * 64 + lane];
        unsigned w1 = Wlb[(4 * q + 1) * 64 + lane];
        unsigned w2 = Wlb[(4 * q + 2) * 64 + lane];
        unsigned w3 = Wlb[(4 * q + 3) * 64 + lane];
        o0 = fmaf(t0, bfLo(w0), o0); o1 = fmaf(t0, bfHi(w0), o1);
        o0 = fmaf(t1, bfLo(w1), o0); o1 = fmaf(t1, bfHi(w1), o1);
        o0 = fmaf(t2, bfLo(w2), o0); o1 = fmaf(t2, bfHi(w2), o1);
        o0 = fmaf(t3, bfLo(w3), o0); o1 = fmaf(t3, bfHi(w3), o1);
      }
      float2 bb = *(const float2*)&bias[2 * lane];
      float r0 = o0 + bb.x, r1 = o1 + bb.y;
      if (RELU) { r0 = fmaxf(r0, 0.f); r1 = fmaxf(r1, 0.f); }
      *(float2*)&out[(size_t)node * 128 + 2 * lane] = make_float2(r0, r1);
    } else {
      float o0 = 0.f;
      const int cp = lane >> 1, hi = lane & 1;
      #pragma unroll
      for (int q = 0; q < 32; q++) {
        float t0 = __shfl(a0, q);
        float t1 = __shfl(a1, q);
        float t2 = __shfl(a2, q);
        float t3 = __shfl(a3, q);
        unsigned w0 = Wlb[(4 * q + 0) * 32 + cp];
        unsigned w1 = Wlb[(4 * q + 1) * 32 + cp];
        unsigned w2 = Wlb[(4 * q + 2) * 32 + cp];
        unsigned w3 = Wlb[(4 * q + 3) * 32 + cp];
        o0 = fmaf(t0, hi ? bfHi(w0) : bfLo(w0), o0);
        o0 = fmaf(t1, hi ? bfHi(w1) : bfLo(w1), o0);
        o0 = fmaf(t2, hi ? bfHi(w2) : bfLo(w2), o0);
        o0 = fmaf(t3, hi ? bfHi(w3) : bfLo(w3), o0);
      }
      float r0 = o0 + bias[lane];
      if (RELU) r0 = fmaxf(r0, 0.f);
      out[(size_t)node * NFO + lane] = r0;
    }
  }
}

// --------------------- fp32 fused kernel (ws-fallback) ---------------------

template <int NFO, bool RELU>
__global__ __launch_bounds__(512) void k_layer_f32(const float* __restrict__ in,
                                                   const float* __restrict__ W,
                                                   const float* __restrict__ bias,
                                                   const float* __restrict__ dinv,
                                                   const int* __restrict__ eSrc,
                                                   const int* __restrict__ rowStart,
                                                   const int* __restrict__ cnt,
                                                   float* __restrict__ out, int n) {
  __shared__ float Wl[128 * NFO];
  for (int t = threadIdx.x; t < 128 * NFO; t += 512) Wl[t] = W[t];
  __syncthreads();
  const int wid = threadIdx.x >> 6, lane = threadIdx.x & 63;
  for (int node = blockIdx.x * 8 + wid; node < n; node += gridDim.x * 8) {
    const int s = rowStart[node], c = cnt[node];
    const int* es = eSrc + s;
    const float dv = dinv[node];
    float2 x2 = *(const float2*)&in[(size_t)node * 128 + 2 * lane];
    float ax = dv * x2.x, ay = dv * x2.y;
    int j = 0;
    for (; j + 4 <= c; j += 4) {
      int s0 = es[j], s1 = es[j + 1], s2 = es[j + 2], s3 = es[j + 3];
      float d0 = dinv[s0], d1 = dinv[s1], d2 = dinv[s2], d3 = dinv[s3];
      float2 v0 = *(const float2*)&in[(size_t)s0 * 128 + 2 * lane];
      float2 v1 = *(const float2*)&in[(size_t)s1 * 128 + 2 * lane];
      float2 v2 = *(const float2*)&in[(size_t)s2 * 128 + 2 * lane];
      float2 v3 = *(const float2*)&in[(size_t)s3 * 128 + 2 * lane];
      ax = fmaf(d0, v0.x, ax); ay = fmaf(d0, v0.y, ay);
      ax = fmaf(d1, v1.x, ax); ay = fmaf(d1, v1.y, ay);
      ax = fmaf(d2, v2.x, ax); ay = fmaf(d2, v2.y, ay);
      ax = fmaf(d3, v3.x, ax); ay = fmaf(d3, v3.y, ay);
    }
    for (; j < c; j++) {
      int sj = es[j];
      float dj = dinv[sj];
      float2 v = *(const float2*)&in[(size_t)sj * 128 + 2 * lane];
      ax = fmaf(dj, v.x, ax); ay = fmaf(dj, v.y, ay);
    }
    ax *= dv; ay *= dv;
    if constexpr (NFO == 128) {
      float o0 = 0.f, o1 = 0.f;
      #pragma unroll
      for (int kk = 0; kk < 64; kk++) {
        float xa = __shfl(ax, kk);
        float xb = __shfl(ay, kk);
        float2 wA = *(const float2*)&Wl[(2 * kk) * 128 + 2 * lane];
        float2 wB = *(const float2*)&Wl[(2 * kk + 1) * 128 + 2 * lane];
        o0 = fmaf(xa, wA.x, o0); o1 = fmaf(xa, wA.y, o1);
        o0 = fmaf(xb, wB.x, o0); o1 = fmaf(xb, wB.y, o1);
      }
      float2 bb = *(const float2*)&bias[2 * lane];
      float r0 = o0 + bb.x, r1 = o1 + bb.y;
      if (RELU) { r0 = fmaxf(r0, 0.f); r1 = fmaxf(r1, 0.f); }
      *(float2*)&out[(size_t)node * 128 + 2 * lane] = make_float2(r0, r1);
    } else {
      float o0 = 0.f;
      #pragma unroll
      for (int kk = 0; kk < 64; kk++) {
        float xa = __shfl(ax, kk);
        float xb = __shfl(ay, kk);
        o0 = fmaf(xa, Wl[(2 * kk) * NFO + lane], o0);
        o0 = fmaf(xb, Wl[(2 * kk + 1) * NFO + lane], o0);
      }
      float r0 = o0 + bias[lane];
      if (RELU) r0 = fmaxf(r0, 0.f);
      out[(size_t)node * NFO + lane] = r0;
    }
  }
}

// ---------------------------------------------------------------------------

extern "C" void kernel_launch(void* const* d_in, const int* in_sizes, int n_in,
                              void* d_out, int out_size, void* d_ws, size_t ws_size,
                              hipStream_t stream) {
  const float* x  = (const float*)d_in[0];
  const int*   ei = (const int*)d_in[1];
  const float* W1 = (const float*)d_in[2];
  const float* b1 = (const float*)d_in[3];
  const float* W2 = (const float*)d_in[4];
  const float* b2 = (const float*)d_in[5];
  const float* W3 = (const float*)d_in[6];
  const float* b3 = (const float*)d_in[7];

  const int N = in_sizes[0] / 128;
  const int E = in_sizes[1] / 2;
  const int* src = ei;
  const int* dst = ei + E;

  char* ws = (char*)d_ws;
  size_t off = 0;
  auto alloc = [&](size_t bytes) -> void* {
    void* p = ws + off;
    off = (off + bytes + 255) & ~(size_t)255;
    return p;
  };
  int*   cnt      = (int*)alloc((size_t)N * 4);
  int*   fillPos  = (int*)alloc((size_t)N * 4);
  int*   rowStart = (int*)alloc((size_t)N * 4);
  float* dinv     = (float*)alloc((size_t)N * 4);
  int*   bsum     = (int*)alloc(512);
  int*   eSrc     = (int*)alloc((size_t)E * 4);
  unsigned* sU    = (unsigned*)alloc((size_t)N * 64 * 4);  // bf16 rows, 256B
  const bool fast = (ws_size >= off);                       // ~33.7 MB

  float* y    = (float*)d_out;          // [N,64]
  float* out1 = y + (size_t)N * 64;     // [N,128]
  float* out2 = out1 + (size_t)N * 128; // [N,128]

  // ---- CSR build ----
  k_zero<<<(N + 255) / 256, 256, 0, stream>>>(cnt, fillPos, N);
  k_deg<<<2048, 256, 0, stream>>>(dst, cnt, E);
  k_dinv<<<(N + 255) / 256, 256, 0, stream>>>(cnt, dinv, N);
  int nChunks = (N + 1023) / 1024;
  k_scan1<<<nChunks, 256, 0, stream>>>(cnt, rowStart, bsum, N);
  k_scan2<<<1, 128, 0, stream>>>(bsum, nChunks);
  k_scan3<<<(N + 255) / 256, 256, 0, stream>>>(rowStart, bsum, N);
  k_fill<<<2048, 256, 0, stream>>>(src, dst, rowStart, fillPos, eSrc, E);

  // ---- layers ----
  if (fast) {
    const int nQuads = N * 16;
    const int sBlocks = (nQuads + 255) / 256;
    k_scale<<<sBlocks, 256, 0, stream>>>(x, dinv, (uint4*)sU, nQuads);
    k_layer_bf7<128, true ><<<1024, 512, 0, stream>>>(sU, W1, b1, dinv, eSrc, rowStart, cnt, out1, N);
    k_scale<<<sBlocks, 256, 0, stream>>>(out1, dinv, (uint4*)sU, nQuads);
    k_layer_bf7<128, true ><<<1024, 512, 0, stream>>>(sU, W2, b2, dinv, eSrc, rowStart, cnt, out2, N);
    k_scale<<<sBlocks, 256, 0, stream>>>(out2, dinv, (uint4*)sU, nQuads);
    k_layer_bf7<64,  false><<<1024, 512, 0, stream>>>(sU, W3, b3, dinv, eSrc, rowStart, cnt, y,    N);
  } else {
    k_layer_f32<128, true ><<<1024, 512, 0, stream>>>(x,    W1, b1, dinv, eSrc, rowStart, cnt, out1, N);
    k_layer_f32<128, true ><<<1024, 512, 0, stream>>>(out1, W2, b2, dinv, eSrc, rowStart, cnt, out2, N);
    k_layer_f32<64,  false><<<1024, 512, 0, stream>>>(out2, W3, b3, dinv, eSrc, rowStart, cnt, y,    N);
  }
}

// Round 16
// 1679.777 us; speedup vs baseline: 3.2291x; 3.2291x over previous
//
#include <hip/hip_runtime.h>
#include <math.h>

// ---------------------------------------------------------------------------
// 3-layer GCN on MI355X, SPLIT aggregate / GEMM form (round-16).
//   out = relu( (A_hat @ in) @ W + b ),  A_hat = D^-1/2 (A+I) D^-1/2
// Evidence through r15: fused gather+GEMM needs >64 VGPR (spills at 64/32);
// occupancy governs random-gather rate (23%->1.15 TB/s, 90%->2.2-2.5 TB/s).
// Split:
//   k_agg  : depth-4 exact-byte bf16 gathers (bf2 body), no LDS, ~40 regs ->
//            (256,8) = 32 waves/CU, VGPR cap 64, no spill. Writes t=bf16.
//   k_gemmT: linear t reads + LDS-bf16 W shfl-GEMM; epilogue writes out fp32
//            AND next layer's prescaled s (bf16) -- k_scale only needed once.
// ws = CSR(8MB) + sU(25.6MB) + t(25.6MB) = 59.2MB, guarded; f32 fused fallback.
// CSR over dst rebuilt on-device every call.
// ---------------------------------------------------------------------------

__device__ __forceinline__ unsigned short f2bf(float f) {
  unsigned u = __float_as_uint(f);
  return (unsigned short)((u + 0x7FFFu + ((u >> 16) & 1u)) >> 16);
}
__device__ __forceinline__ float bfLo(unsigned v) { return __uint_as_float(v << 16); }
__device__ __forceinline__ float bfHi(unsigned v) { return __uint_as_float(v & 0xFFFF0000u); }

// ------------------------------- CSR build ---------------------------------

__global__ __launch_bounds__(256) void k_zero(int* __restrict__ cnt,
                                              int* __restrict__ fillPos, int n) {
  int i = blockIdx.x * blockDim.x + threadIdx.x;
  if (i < n) { cnt[i] = 0; fillPos[i] = 0; }
}

__global__ __launch_bounds__(256) void k_deg(const int* __restrict__ dst,
                                             int* __restrict__ cnt, int E) {
  int i = blockIdx.x * blockDim.x + threadIdx.x;
  int stride = gridDim.x * blockDim.x;
  for (; i < E; i += stride) atomicAdd(&cnt[dst[i]], 1);
}

__global__ __launch_bounds__(256) void k_dinv(const int* __restrict__ cnt,
                                              float* __restrict__ dinv, int n) {
  int i = blockIdx.x * blockDim.x + threadIdx.x;
  if (i < n) dinv[i] = rsqrtf(1.0f + (float)cnt[i]);
}

__global__ __launch_bounds__(256) void k_scan1(const int* __restrict__ cnt,
                                               int* __restrict__ exc,
                                               int* __restrict__ bsum, int n) {
  __shared__ int lds[256];
  int t = threadIdx.x;
  int base = blockIdx.x * 1024 + t * 4;
  int v0 = (base + 0 < n) ? cnt[base + 0] : 0;
  int v1 = (base + 1 < n) ? cnt[base + 1] : 0;
  int v2 = (base + 2 < n) ? cnt[base + 2] : 0;
  int v3 = (base + 3 < n) ? cnt[base + 3] : 0;
  int sum = v0 + v1 + v2 + v3;
  lds[t] = sum;
  __syncthreads();
  for (int off = 1; off < 256; off <<= 1) {
    int val = lds[t];
    if (t >= off) val += lds[t - off];
    __syncthreads();
    lds[t] = val;
    __syncthreads();
  }
  int ex = lds[t] - sum;
  if (base + 0 < n) exc[base + 0] = ex;
  ex += v0;
  if (base + 1 < n) exc[base + 1] = ex;
  ex += v1;
  if (base + 2 < n) exc[base + 2] = ex;
  ex += v2;
  if (base + 3 < n) exc[base + 3] = ex;
  if (t == 255) bsum[blockIdx.x] = lds[255];
}

__global__ __launch_bounds__(128) void k_scan2(int* __restrict__ bsum, int nb) {
  __shared__ int lds[128];
  int t = threadIdx.x;
  int v = (t < nb) ? bsum[t] : 0;
  lds[t] = v;
  __syncthreads();
  for (int off = 1; off < 128; off <<= 1) {
    int val = lds[t];
    if (t >= off) val += lds[t - off];
    __syncthreads();
    lds[t] = val;
    __syncthreads();
  }
  if (t < nb) bsum[t] = lds[t] - v;
}

__global__ __launch_bounds__(256) void k_scan3(int* __restrict__ exc,
                                               const int* __restrict__ bsum, int n) {
  int i = blockIdx.x * blockDim.x + threadIdx.x;
  if (i < n) exc[i] += bsum[i >> 10];
}

__global__ __launch_bounds__(256) void k_fill(const int* __restrict__ src,
                                              const int* __restrict__ dst,
                                              const int* __restrict__ rowStart,
                                              int* __restrict__ fillPos,
                                              int* __restrict__ eSrc, int E) {
  int i = blockIdx.x * blockDim.x + threadIdx.x;
  int stride = gridDim.x * blockDim.x;
  for (; i < E; i += stride) {
    int d = dst[i];
    int p = rowStart[d] + atomicAdd(&fillPos[d], 1);
    eSrc[p] = src[i];
  }
}

// ---------------- bf16 prescale: s = bf16(dinv * h), 256B rows -------------

__global__ __launch_bounds__(256) void k_scale(const float* __restrict__ h,
                                               const float* __restrict__ dinv,
                                               uint4* __restrict__ s4, int nQuads) {
  int i = blockIdx.x * blockDim.x + threadIdx.x;
  int stride = gridDim.x * blockDim.x;
  for (; i < nQuads; i += stride) {
    int row = i >> 4;
    int q = i & 15;
    float dv = dinv[row];
    const float4* hp = (const float4*)&h[(size_t)row * 128 + 8 * q];
    float4 a = hp[0], b = hp[1];
    uint4 o;
    o.x = (unsigned)f2bf(dv * a.x) | ((unsigned)f2bf(dv * a.y) << 16);
    o.y = (unsigned)f2bf(dv * a.z) | ((unsigned)f2bf(dv * a.w) << 16);
    o.z = (unsigned)f2bf(dv * b.x) | ((unsigned)f2bf(dv * b.y) << 16);
    o.w = (unsigned)f2bf(dv * b.z) | ((unsigned)f2bf(dv * b.w) << 16);
    s4[i] = o;
  }
}

// ---- k_agg: gather-only, depth-4 pairs, no LDS, 32 waves/CU ---------------
// Lane l: half=l>>5, sl=l&31; lane owns bf16 cols 4sl..4sl+3 of s.
// t[node] = bf16( dinv[node] * (sum_{src->node} s[src] + s[node]) )
__global__ __launch_bounds__(256, 8) void k_agg(const unsigned* __restrict__ sU,
                                                const float* __restrict__ dinv,
                                                const int* __restrict__ eSrc,
                                                const int* __restrict__ rowStart,
                                                const int* __restrict__ cnt,
                                                unsigned* __restrict__ tB, int n) {
  const int wid = threadIdx.x >> 6, lane = threadIdx.x & 63;
  const int half = lane >> 5, sl = lane & 31;
  for (int node = blockIdx.x * 4 + wid; node < n; node += gridDim.x * 4) {
    const int st = rowStart[node], c = cnt[node];
    const int* es = eSrc + st;
    const float dv = dinv[node];
    uint2 vs = *(const uint2*)&sU[(size_t)node * 64 + 2 * sl];  // self row
    float a0, a1, a2, a3;
    if (half == 0) {
      a0 = bfLo(vs.x); a1 = bfHi(vs.x); a2 = bfLo(vs.y); a3 = bfHi(vs.y);
    } else {
      a0 = a1 = a2 = a3 = 0.f;
    }
    const int cl = c < 64 ? c : 64;
    int myIdx = (lane < cl) ? es[lane] : 0;
    int j = 0;
    for (; j + 8 <= cl; j += 8) {  // 4 independent pair-loads = 8 edges
      int iA0 = __shfl(myIdx, j + 0), iB0 = __shfl(myIdx, j + 1);
      int iA1 = __shfl(myIdx, j + 2), iB1 = __shfl(myIdx, j + 3);
      int iA2 = __shfl(myIdx, j + 4), iB2 = __shfl(myIdx, j + 5);
      int iA3 = __shfl(myIdx, j + 6), iB3 = __shfl(myIdx, j + 7);
      int x0 = half ? iB0 : iA0;
      int x1 = half ? iB1 : iA1;
      int x2 = half ? iB2 : iA2;
      int x3 = half ? iB3 : iA3;
      uint2 v0 = *(const uint2*)&sU[(size_t)x0 * 64 + 2 * sl];
      uint2 v1 = *(const uint2*)&sU[(size_t)x1 * 64 + 2 * sl];
      uint2 v2 = *(const uint2*)&sU[(size_t)x2 * 64 + 2 * sl];
      uint2 v3 = *(const uint2*)&sU[(size_t)x3 * 64 + 2 * sl];
      a0 += bfLo(v0.x); a1 += bfHi(v0.x); a2 += bfLo(v0.y); a3 += bfHi(v0.y);
      a0 += bfLo(v1.x); a1 += bfHi(v1.x); a2 += bfLo(v1.y); a3 += bfHi(v1.y);
      a0 += bfLo(v2.x); a1 += bfHi(v2.x); a2 += bfLo(v2.y); a3 += bfHi(v2.y);
      a0 += bfLo(v3.x); a1 += bfHi(v3.x); a2 += bfLo(v3.y); a3 += bfHi(v3.y);
    }
    for (; j < c; j += 2) {  // pair tail (odd c and c>64)
      int iA = (j < cl) ? __shfl(myIdx, j) : es[j];
      int hasB = (j + 1 < c);
      int iB = hasB ? ((j + 1 < cl) ? __shfl(myIdx, j + 1) : es[j + 1]) : iA;
      int x = half ? iB : iA;
      uint2 v = *(const uint2*)&sU[(size_t)x * 64 + 2 * sl];
      if (half && !hasB) { v.x = 0u; v.y = 0u; }
      a0 += bfLo(v.x); a1 += bfHi(v.x); a2 += bfLo(v.y); a3 += bfHi(v.y);
    }
    a0 += __shfl_xor(a0, 32);
    a1 += __shfl_xor(a1, 32);
    a2 += __shfl_xor(a2, 32);
    a3 += __shfl_xor(a3, 32);
    if (half == 0) {  // pack & store t row (256B, 32 lanes x uint2)
      uint2 o;
      o.x = (unsigned)f2bf(dv * a0) | ((unsigned)f2bf(dv * a1) << 16);
      o.y = (unsigned)f2bf(dv * a2) | ((unsigned)f2bf(dv * a3) << 16);
      *(uint2*)&tB[(size_t)node * 64 + 2 * sl] = o;
    }
  }
}

// ---- k_gemmT: t (bf16 rows) @ W (bf16 LDS) + b -> out fp32 [+ sNext bf16] --
// Lane l: reads t uint2 at 2*(l&31) -> both halves hold cols 4sl..4sl+3.
// GEMM: t[4q+r] broadcast from lane q; out cols 2l,2l+1 (NFO=128) / col l.
template <int NFO, bool RELU, bool WRITE_S>
__global__ __launch_bounds__(512) void k_gemmT(const unsigned* __restrict__ tB,
                                               const float* __restrict__ W,
                                               const float* __restrict__ bias,
                                               const float* __restrict__ dinv,
                                               float* __restrict__ out,
                                               unsigned* __restrict__ sNext, int n) {
  __shared__ unsigned Wlb[64 * NFO];  // 128 rows x NFO/2 packed bf16 pairs
  for (int t = threadIdx.x; t < 64 * NFO; t += 512) {
    float2 w2 = *(const float2*)&W[2 * t];
    Wlb[t] = (unsigned)f2bf(w2.x) | ((unsigned)f2bf(w2.y) << 16);
  }
  __syncthreads();
  const int wid = threadIdx.x >> 6, lane = threadIdx.x & 63;
  const int sl = lane & 31;
  for (int node = blockIdx.x * 8 + wid; node < n; node += gridDim.x * 8) {
    uint2 tv = *(const uint2*)&tB[(size_t)node * 64 + 2 * sl];
    float a0 = bfLo(tv.x), a1 = bfHi(tv.x), a2 = bfLo(tv.y), a3 = bfHi(tv.y);
    if constexpr (NFO == 128) {
      float o0 = 0.f, o1 = 0.f;
      #pragma unroll
      for (int q = 0; q < 32; q++) {
        float t0 = __shfl(a0, q);
        float t1 = __shfl(a1, q);
        float t2 = __shfl(a2, q);
        float t3 = __shfl(a3, q);
        unsigned w0 = Wlb[(4 * q + 0) * 64 + lane];
        unsigned w1 = Wlb[(4 * q + 1) * 64 + lane];
        unsigned w2 = Wlb[(4 * q + 2) * 64 + lane];
        unsigned w3 = Wlb[(4 * q + 3) * 64 + lane];
        o0 = fmaf(t0, bfLo(w0), o0); o1 = fmaf(t0, bfHi(w0), o1);
        o0 = fmaf(t1, bfLo(w1), o0); o1 = fmaf(t1, bfHi(w1), o1);
        o0 = fmaf(t2, bfLo(w2), o0); o1 = fmaf(t2, bfHi(w2), o1);
        o0 = fmaf(t3, bfLo(w3), o0); o1 = fmaf(t3, bfHi(w3), o1);
      }
      float2 bb = *(const float2*)&bias[2 * lane];
      float r0 = o0 + bb.x, r1 = o1 + bb.y;
      if (RELU) { r0 = fmaxf(r0, 0.f); r1 = fmaxf(r1, 0.f); }
      *(float2*)&out[(size_t)node * 128 + 2 * lane] = make_float2(r0, r1);
      if (WRITE_S) {  // next layer's prescaled gather rows
        float dv = dinv[node];
        sNext[(size_t)node * 64 + lane] =
            (unsigned)f2bf(dv * r0) | ((unsigned)f2bf(dv * r1) << 16);
      }
    } else {
      float o0 = 0.f;
      const int cp = lane >> 1, hi = lane & 1;
      #pragma unroll
      for (int q = 0; q < 32; q++) {
        float t0 = __shfl(a0, q);
        float t1 = __shfl(a1, q);
        float t2 = __shfl(a2, q);
        float t3 = __shfl(a3, q);
        unsigned w0 = Wlb[(4 * q + 0) * 32 + cp];
        unsigned w1 = Wlb[(4 * q + 1) * 32 + cp];
        unsigned w2 = Wlb[(4 * q + 2) * 32 + cp];
        unsigned w3 = Wlb[(4 * q + 3) * 32 + cp];
        o0 = fmaf(t0, hi ? bfHi(w0) : bfLo(w0), o0);
        o0 = fmaf(t1, hi ? bfHi(w1) : bfLo(w1), o0);
        o0 = fmaf(t2, hi ? bfHi(w2) : bfLo(w2), o0);
        o0 = fmaf(t3, hi ? bfHi(w3) : bfLo(w3), o0);
      }
      float r0 = o0 + bias[lane];
      if (RELU) r0 = fmaxf(r0, 0.f);
      out[(size_t)node * NFO + lane] = r0;
    }
  }
}

// --------------------- fp32 fused kernel (ws-fallback) ---------------------

template <int NFO, bool RELU>
__global__ __launch_bounds__(512) void k_layer_f32(const float* __restrict__ in,
                                                   const float* __restrict__ W,
                                                   const float* __restrict__ bias,
                                                   const float* __restrict__ dinv,
                                                   const int* __restrict__ eSrc,
                                                   const int* __restrict__ rowStart,
                                                   const int* __restrict__ cnt,
                                                   float* __restrict__ out, int n) {
  __shared__ float Wl[128 * NFO];
  for (int t = threadIdx.x; t < 128 * NFO; t += 512) Wl[t] = W[t];
  __syncthreads();
  const int wid = threadIdx.x >> 6, lane = threadIdx.x & 63;
  for (int node = blockIdx.x * 8 + wid; node < n; node += gridDim.x * 8) {
    const int s = rowStart[node], c = cnt[node];
    const int* es = eSrc + s;
    const float dv = dinv[node];
    float2 x2 = *(const float2*)&in[(size_t)node * 128 + 2 * lane];
    float ax = dv * x2.x, ay = dv * x2.y;
    int j = 0;
    for (; j + 4 <= c; j += 4) {
      int s0 = es[j], s1 = es[j + 1], s2 = es[j + 2], s3 = es[j + 3];
      float d0 = dinv[s0], d1 = dinv[s1], d2 = dinv[s2], d3 = dinv[s3];
      float2 v0 = *(const float2*)&in[(size_t)s0 * 128 + 2 * lane];
      float2 v1 = *(const float2*)&in[(size_t)s1 * 128 + 2 * lane];
      float2 v2 = *(const float2*)&in[(size_t)s2 * 128 + 2 * lane];
      float2 v3 = *(const float2*)&in[(size_t)s3 * 128 + 2 * lane];
      ax = fmaf(d0, v0.x, ax); ay = fmaf(d0, v0.y, ay);
      ax = fmaf(d1, v1.x, ax); ay = fmaf(d1, v1.y, ay);
      ax = fmaf(d2, v2.x, ax); ay = fmaf(d2, v2.y, ay);
      ax = fmaf(d3, v3.x, ax); ay = fmaf(d3, v3.y, ay);
    }
    for (; j < c; j++) {
      int sj = es[j];
      float dj = dinv[sj];
      float2 v = *(const float2*)&in[(size_t)sj * 128 + 2 * lane];
      ax = fmaf(dj, v.x, ax); ay = fmaf(dj, v.y, ay);
    }
    ax *= dv; ay *= dv;
    if constexpr (NFO == 128) {
      float o0 = 0.f, o1 = 0.f;
      #pragma unroll
      for (int kk = 0; kk < 64; kk++) {
        float xa = __shfl(ax, kk);
        float xb = __shfl(ay, kk);
        float2 wA = *(const float2*)&Wl[(2 * kk) * 128 + 2 * lane];
        float2 wB = *(const float2*)&Wl[(2 * kk + 1) * 128 + 2 * lane];
        o0 = fmaf(xa, wA.x, o0); o1 = fmaf(xa, wA.y, o1);
        o0 = fmaf(xb, wB.x, o0); o1 = fmaf(xb, wB.y, o1);
      }
      float2 bb = *(const float2*)&bias[2 * lane];
      float r0 = o0 + bb.x, r1 = o1 + bb.y;
      if (RELU) { r0 = fmaxf(r0, 0.f); r1 = fmaxf(r1, 0.f); }
      *(float2*)&out[(size_t)node * 128 + 2 * lane] = make_float2(r0, r1);
    } else {
      float o0 = 0.f;
      #pragma unroll
      for (int kk = 0; kk < 64; kk++) {
        float xa = __shfl(ax, kk);
        float xb = __shfl(ay, kk);
        o0 = fmaf(xa, Wl[(2 * kk) * NFO + lane], o0);
        o0 = fmaf(xb, Wl[(2 * kk + 1) * NFO + lane], o0);
      }
      float r0 = o0 + bias[lane];
      if (RELU) r0 = fmaxf(r0, 0.f);
      out[(size_t)node * NFO + lane] = r0;
    }
  }
}

// ---------------------------------------------------------------------------

extern "C" void kernel_launch(void* const* d_in, const int* in_sizes, int n_in,
                              void* d_out, int out_size, void* d_ws, size_t ws_size,
                              hipStream_t stream) {
  const float* x  = (const float*)d_in[0];
  const int*   ei = (const int*)d_in[1];
  const float* W1 = (const float*)d_in[2];
  const float* b1 = (const float*)d_in[3];
  const float* W2 = (const float*)d_in[4];
  const float* b2 = (const float*)d_in[5];
  const float* W3 = (const float*)d_in[6];
  const float* b3 = (const float*)d_in[7];

  const int N = in_sizes[0] / 128;
  const int E = in_sizes[1] / 2;
  const int* src = ei;
  const int* dst = ei + E;

  char* ws = (char*)d_ws;
  size_t off = 0;
  auto alloc = [&](size_t bytes) -> void* {
    void* p = ws + off;
    off = (off + bytes + 255) & ~(size_t)255;
    return p;
  };
  int*   cnt      = (int*)alloc((size_t)N * 4);
  int*   fillPos  = (int*)alloc((size_t)N * 4);
  int*   rowStart = (int*)alloc((size_t)N * 4);
  float* dinv     = (float*)alloc((size_t)N * 4);
  int*   bsum     = (int*)alloc(512);
  int*   eSrc     = (int*)alloc((size_t)E * 4);
  unsigned* sU    = (unsigned*)alloc((size_t)N * 64 * 4);  // s rows, bf16, 256B
  unsigned* tB    = (unsigned*)alloc((size_t)N * 64 * 4);  // t rows, bf16, 256B
  const bool fast = (ws_size >= off);                       // ~59.2 MB

  float* y    = (float*)d_out;          // [N,64]
  float* out1 = y + (size_t)N * 64;     // [N,128]
  float* out2 = out1 + (size_t)N * 128; // [N,128]

  // ---- CSR build ----
  k_zero<<<(N + 255) / 256, 256, 0, stream>>>(cnt, fillPos, N);
  k_deg<<<2048, 256, 0, stream>>>(dst, cnt, E);
  k_dinv<<<(N + 255) / 256, 256, 0, stream>>>(cnt, dinv, N);
  int nChunks = (N + 1023) / 1024;
  k_scan1<<<nChunks, 256, 0, stream>>>(cnt, rowStart, bsum, N);
  k_scan2<<<1, 128, 0, stream>>>(bsum, nChunks);
  k_scan3<<<(N + 255) / 256, 256, 0, stream>>>(rowStart, bsum, N);
  k_fill<<<2048, 256, 0, stream>>>(src, dst, rowStart, fillPos, eSrc, E);

  if (fast) {
    const int aggBlocks = (N + 3) / 4;
    k_scale<<<(N * 16 + 255) / 256, 256, 0, stream>>>(x, dinv, (uint4*)sU, N * 16);
    // L1
    k_agg<<<aggBlocks, 256, 0, stream>>>(sU, dinv, eSrc, rowStart, cnt, tB, N);
    k_gemmT<128, true, true><<<1024, 512, 0, stream>>>(tB, W1, b1, dinv, out1, sU, N);
    // L2
    k_agg<<<aggBlocks, 256, 0, stream>>>(sU, dinv, eSrc, rowStart, cnt, tB, N);
    k_gemmT<128, true, true><<<1024, 512, 0, stream>>>(tB, W2, b2, dinv, out2, sU, N);
    // L3
    k_agg<<<aggBlocks, 256, 0, stream>>>(sU, dinv, eSrc, rowStart, cnt, tB, N);
    k_gemmT<64, false, false><<<1024, 512, 0, stream>>>(tB, W3, b3, dinv, y, nullptr, N);
  } else {
    k_layer_f32<128, true ><<<1024, 512, 0, stream>>>(x,    W1, b1, dinv, eSrc, rowStart, cnt, out1, N);
    k_layer_f32<128, true ><<<1024, 512, 0, stream>>>(out1, W2, b2, dinv, eSrc, rowStart, cnt, out2, N);
    k_layer_f32<64,  false><<<1024, 512, 0, stream>>>(out2, W3, b3, dinv, eSrc, rowStart, cnt, y,    N);
  }
}

// Round 20
// 911.925 us; speedup vs baseline: 5.9480x; 1.8420x over previous
//
#include <hip/hip_runtime.h>
#include <math.h>

// ---------------------------------------------------------------------------
// 3-layer GCN on MI355X, SPLIT aggregate / GEMM form (round-20 = round-17
// re-land; three consecutive infra failures, kernel unchanged).
//   out = relu( (A_hat @ in) @ W + b ),  A_hat = D^-1/2 (A+I) D^-1/2
//   k_agg  : depth-4 exact-byte bf16 gathers, no LDS, 32 waves/CU (proven
//            r16: dropped out of top-5).
//   k_gemmT: linear t reads + LDS-bf16 W shfl-GEMM. r16 exposed a spill
//            (~200B/thread scratch: WRITE 183MB vs 77 expected) from the
//            FULLY-unrolled 32-iter GEMM loop -- present since r8, hidden
//            under gather latency. Fix: #pragma unroll 4 bounds the live
//            set to ~45 regs. One-variable change vs r16.
// CSR over dst rebuilt on-device every call.
// ---------------------------------------------------------------------------

__device__ __forceinline__ unsigned short f2bf(float f) {
  unsigned u = __float_as_uint(f);
  return (unsigned short)((u + 0x7FFFu + ((u >> 16) & 1u)) >> 16);
}
__device__ __forceinline__ float bfLo(unsigned v) { return __uint_as_float(v << 16); }
__device__ __forceinline__ float bfHi(unsigned v) { return __uint_as_float(v & 0xFFFF0000u); }

// ------------------------------- CSR build ---------------------------------

__global__ __launch_bounds__(256) void k_zero(int* __restrict__ cnt,
                                              int* __restrict__ fillPos, int n) {
  int i = blockIdx.x * blockDim.x + threadIdx.x;
  if (i < n) { cnt[i] = 0; fillPos[i] = 0; }
}

__global__ __launch_bounds__(256) void k_deg(const int* __restrict__ dst,
                                             int* __restrict__ cnt, int E) {
  int i = blockIdx.x * blockDim.x + threadIdx.x;
  int stride = gridDim.x * blockDim.x;
  for (; i < E; i += stride) atomicAdd(&cnt[dst[i]], 1);
}

__global__ __launch_bounds__(256) void k_dinv(const int* __restrict__ cnt,
                                              float* __restrict__ dinv, int n) {
  int i = blockIdx.x * blockDim.x + threadIdx.x;
  if (i < n) dinv[i] = rsqrtf(1.0f + (float)cnt[i]);
}

__global__ __launch_bounds__(256) void k_scan1(const int* __restrict__ cnt,
                                               int* __restrict__ exc,
                                               int* __restrict__ bsum, int n) {
  __shared__ int lds[256];
  int t = threadIdx.x;
  int base = blockIdx.x * 1024 + t * 4;
  int v0 = (base + 0 < n) ? cnt[base + 0] : 0;
  int v1 = (base + 1 < n) ? cnt[base + 1] : 0;
  int v2 = (base + 2 < n) ? cnt[base + 2] : 0;
  int v3 = (base + 3 < n) ? cnt[base + 3] : 0;
  int sum = v0 + v1 + v2 + v3;
  lds[t] = sum;
  __syncthreads();
  for (int off = 1; off < 256; off <<= 1) {
    int val = lds[t];
    if (t >= off) val += lds[t - off];
    __syncthreads();
    lds[t] = val;
    __syncthreads();
  }
  int ex = lds[t] - sum;
  if (base + 0 < n) exc[base + 0] = ex;
  ex += v0;
  if (base + 1 < n) exc[base + 1] = ex;
  ex += v1;
  if (base + 2 < n) exc[base + 2] = ex;
  ex += v2;
  if (base + 3 < n) exc[base + 3] = ex;
  if (t == 255) bsum[blockIdx.x] = lds[255];
}

__global__ __launch_bounds__(128) void k_scan2(int* __restrict__ bsum, int nb) {
  __shared__ int lds[128];
  int t = threadIdx.x;
  int v = (t < nb) ? bsum[t] : 0;
  lds[t] = v;
  __syncthreads();
  for (int off = 1; off < 128; off <<= 1) {
    int val = lds[t];
    if (t >= off) val += lds[t - off];
    __syncthreads();
    lds[t] = val;
    __syncthreads();
  }
  if (t < nb) bsum[t] = lds[t] - v;
}

__global__ __launch_bounds__(256) void k_scan3(int* __restrict__ exc,
                                               const int* __restrict__ bsum, int n) {
  int i = blockIdx.x * blockDim.x + threadIdx.x;
  if (i < n) exc[i] += bsum[i >> 10];
}

__global__ __launch_bounds__(256) void k_fill(const int* __restrict__ src,
                                              const int* __restrict__ dst,
                                              const int* __restrict__ rowStart,
                                              int* __restrict__ fillPos,
                                              int* __restrict__ eSrc, int E) {
  int i = blockIdx.x * blockDim.x + threadIdx.x;
  int stride = gridDim.x * blockDim.x;
  for (; i < E; i += stride) {
    int d = dst[i];
    int p = rowStart[d] + atomicAdd(&fillPos[d], 1);
    eSrc[p] = src[i];
  }
}

// ---------------- bf16 prescale: s = bf16(dinv * h), 256B rows -------------

__global__ __launch_bounds__(256) void k_scale(const float* __restrict__ h,
                                               const float* __restrict__ dinv,
                                               uint4* __restrict__ s4, int nQuads) {
  int i = blockIdx.x * blockDim.x + threadIdx.x;
  int stride = gridDim.x * blockDim.x;
  for (; i < nQuads; i += stride) {
    int row = i >> 4;
    int q = i & 15;
    float dv = dinv[row];
    const float4* hp = (const float4*)&h[(size_t)row * 128 + 8 * q];
    float4 a = hp[0], b = hp[1];
    uint4 o;
    o.x = (unsigned)f2bf(dv * a.x) | ((unsigned)f2bf(dv * a.y) << 16);
    o.y = (unsigned)f2bf(dv * a.z) | ((unsigned)f2bf(dv * a.w) << 16);
    o.z = (unsigned)f2bf(dv * b.x) | ((unsigned)f2bf(dv * b.y) << 16);
    o.w = (unsigned)f2bf(dv * b.z) | ((unsigned)f2bf(dv * b.w) << 16);
    s4[i] = o;
  }
}

// ---- k_agg: gather-only, depth-4 pairs, no LDS, 32 waves/CU ---------------
__global__ __launch_bounds__(256, 8) void k_agg(const unsigned* __restrict__ sU,
                                                const float* __restrict__ dinv,
                                                const int* __restrict__ eSrc,
                                                const int* __restrict__ rowStart,
                                                const int* __restrict__ cnt,
                                                unsigned* __restrict__ tB, int n) {
  const int wid = threadIdx.x >> 6, lane = threadIdx.x & 63;
  const int half = lane >> 5, sl = lane & 31;
  for (int node = blockIdx.x * 4 + wid; node < n; node += gridDim.x * 4) {
    const int st = rowStart[node], c = cnt[node];
    const int* es = eSrc + st;
    const float dv = dinv[node];
    uint2 vs = *(const uint2*)&sU[(size_t)node * 64 + 2 * sl];  // self row
    float a0, a1, a2, a3;
    if (half == 0) {
      a0 = bfLo(vs.x); a1 = bfHi(vs.x); a2 = bfLo(vs.y); a3 = bfHi(vs.y);
    } else {
      a0 = a1 = a2 = a3 = 0.f;
    }
    const int cl = c < 64 ? c : 64;
    int myIdx = (lane < cl) ? es[lane] : 0;
    int j = 0;
    for (; j + 8 <= cl; j += 8) {  // 4 independent pair-loads = 8 edges
      int iA0 = __shfl(myIdx, j + 0), iB0 = __shfl(myIdx, j + 1);
      int iA1 = __shfl(myIdx, j + 2), iB1 = __shfl(myIdx, j + 3);
      int iA2 = __shfl(myIdx, j + 4), iB2 = __shfl(myIdx, j + 5);
      int iA3 = __shfl(myIdx, j + 6), iB3 = __shfl(myIdx, j + 7);
      int x0 = half ? iB0 : iA0;
      int x1 = half ? iB1 : iA1;
      int x2 = half ? iB2 : iA2;
      int x3 = half ? iB3 : iA3;
      uint2 v0 = *(const uint2*)&sU[(size_t)x0 * 64 + 2 * sl];
      uint2 v1 = *(const uint2*)&sU[(size_t)x1 * 64 + 2 * sl];
      uint2 v2 = *(const uint2*)&sU[(size_t)x2 * 64 + 2 * sl];
      uint2 v3 = *(const uint2*)&sU[(size_t)x3 * 64 + 2 * sl];
      a0 += bfLo(v0.x); a1 += bfHi(v0.x); a2 += bfLo(v0.y); a3 += bfHi(v0.y);
      a0 += bfLo(v1.x); a1 += bfHi(v1.x); a2 += bfLo(v1.y); a3 += bfHi(v1.y);
      a0 += bfLo(v2.x); a1 += bfHi(v2.x); a2 += bfLo(v2.y); a3 += bfHi(v2.y);
      a0 += bfLo(v3.x); a1 += bfHi(v3.x); a2 += bfLo(v3.y); a3 += bfHi(v3.y);
    }
    for (; j < c; j += 2) {  // pair tail (odd c and c>64)
      int iA = (j < cl) ? __shfl(myIdx, j) : es[j];
      int hasB = (j + 1 < c);
      int iB = hasB ? ((j + 1 < cl) ? __shfl(myIdx, j + 1) : es[j + 1]) : iA;
      int x = half ? iB : iA;
      uint2 v = *(const uint2*)&sU[(size_t)x * 64 + 2 * sl];
      if (half && !hasB) { v.x = 0u; v.y = 0u; }
      a0 += bfLo(v.x); a1 += bfHi(v.x); a2 += bfLo(v.y); a3 += bfHi(v.y);
    }
    a0 += __shfl_xor(a0, 32);
    a1 += __shfl_xor(a1, 32);
    a2 += __shfl_xor(a2, 32);
    a3 += __shfl_xor(a3, 32);
    if (half == 0) {  // pack & store t row (256B, 32 lanes x uint2)
      uint2 o;
      o.x = (unsigned)f2bf(dv * a0) | ((unsigned)f2bf(dv * a1) << 16);
      o.y = (unsigned)f2bf(dv * a2) | ((unsigned)f2bf(dv * a3) << 16);
      *(uint2*)&tB[(size_t)node * 64 + 2 * sl] = o;
    }
  }
}

// ---- k_gemmT: t (bf16 rows) @ W (bf16 LDS) + b -> out fp32 [+ sNext bf16] --
// r17 fix: #pragma unroll 4 (full unroll spilled ~200B/thread since r8).
template <int NFO, bool RELU, bool WRITE_S>
__global__ __launch_bounds__(512) void k_gemmT(const unsigned* __restrict__ tB,
                                               const float* __restrict__ W,
                                               const float* __restrict__ bias,
                                               const float* __restrict__ dinv,
                                               float* __restrict__ out,
                                               unsigned* __restrict__ sNext, int n) {
  __shared__ unsigned Wlb[64 * NFO];  // 128 rows x NFO/2 packed bf16 pairs
  for (int t = threadIdx.x; t < 64 * NFO; t += 512) {
    float2 w2 = *(const float2*)&W[2 * t];
    Wlb[t] = (unsigned)f2bf(w2.x) | ((unsigned)f2bf(w2.y) << 16);
  }
  __syncthreads();
  const int wid = threadIdx.x >> 6, lane = threadIdx.x & 63;
  const int sl = lane & 31;
  for (int node = blockIdx.x * 8 + wid; node < n; node += gridDim.x * 8) {
    uint2 tv = *(const uint2*)&tB[(size_t)node * 64 + 2 * sl];
    float a0 = bfLo(tv.x), a1 = bfHi(tv.x), a2 = bfLo(tv.y), a3 = bfHi(tv.y);
    if constexpr (NFO == 128) {
      float o0 = 0.f, o1 = 0.f;
      #pragma unroll 4
      for (int q = 0; q < 32; q++) {
        float t0 = __shfl(a0, q);
        float t1 = __shfl(a1, q);
        float t2 = __shfl(a2, q);
        float t3 = __shfl(a3, q);
        unsigned w0 = Wlb[(4 * q + 0) * 64 + lane];
        unsigned w1 = Wlb[(4 * q + 1) * 64 + lane];
        unsigned w2 = Wlb[(4 * q + 2) * 64 + lane];
        unsigned w3 = Wlb[(4 * q + 3) * 64 + lane];
        o0 = fmaf(t0, bfLo(w0), o0); o1 = fmaf(t0, bfHi(w0), o1);
        o0 = fmaf(t1, bfLo(w1), o0); o1 = fmaf(t1, bfHi(w1), o1);
        o0 = fmaf(t2, bfLo(w2), o0); o1 = fmaf(t2, bfHi(w2), o1);
        o0 = fmaf(t3, bfLo(w3), o0); o1 = fmaf(t3, bfHi(w3), o1);
      }
      float2 bb = *(const float2*)&bias[2 * lane];
      float r0 = o0 + bb.x, r1 = o1 + bb.y;
      if (RELU) { r0 = fmaxf(r0, 0.f); r1 = fmaxf(r1, 0.f); }
      *(float2*)&out[(size_t)node * 128 + 2 * lane] = make_float2(r0, r1);
      if (WRITE_S) {  // next layer's prescaled gather rows
        float dv = dinv[node];
        sNext[(size_t)node * 64 + lane] =
            (unsigned)f2bf(dv * r0) | ((unsigned)f2bf(dv * r1) << 16);
      }
    } else {
      float o0 = 0.f;
      const int cp = lane >> 1, hi = lane & 1;
      #pragma unroll 4
      for (int q = 0; q < 32; q++) {
        float t0 = __shfl(a0, q);
        float t1 = __shfl(a1, q);
        float t2 = __shfl(a2, q);
        float t3 = __shfl(a3, q);
        unsigned w0 = Wlb[(4 * q + 0) * 32 + cp];
        unsigned w1 = Wlb[(4 * q + 1) * 32 + cp];
        unsigned w2 = Wlb[(4 * q + 2) * 32 + cp];
        unsigned w3 = Wlb[(4 * q + 3) * 32 + cp];
        o0 = fmaf(t0, hi ? bfHi(w0) : bfLo(w0), o0);
        o0 = fmaf(t1, hi ? bfHi(w1) : bfLo(w1), o0);
        o0 = fmaf(t2, hi ? bfHi(w2) : bfLo(w2), o0);
        o0 = fmaf(t3, hi ? bfHi(w3) : bfLo(w3), o0);
      }
      float r0 = o0 + bias[lane];
      if (RELU) r0 = fmaxf(r0, 0.f);
      out[(size_t)node * NFO + lane] = r0;
    }
  }
}

// --------------------- fp32 fused kernel (ws-fallback) ---------------------

template <int NFO, bool RELU>
__global__ __launch_bounds__(512) void k_layer_f32(const float* __restrict__ in,
                                                   const float* __restrict__ W,
                                                   const float* __restrict__ bias,
                                                   const float* __restrict__ dinv,
                                                   const int* __restrict__ eSrc,
                                                   const int* __restrict__ rowStart,
                                                   const int* __restrict__ cnt,
                                                   float* __restrict__ out, int n) {
  __shared__ float Wl[128 * NFO];
  for (int t = threadIdx.x; t < 128 * NFO; t += 512) Wl[t] = W[t];
  __syncthreads();
  const int wid = threadIdx.x >> 6, lane = threadIdx.x & 63;
  for (int node = blockIdx.x * 8 + wid; node < n; node += gridDim.x * 8) {
    const int s = rowStart[node], c = cnt[node];
    const int* es = eSrc + s;
    const float dv = dinv[node];
    float2 x2 = *(const float2*)&in[(size_t)node * 128 + 2 * lane];
    float ax = dv * x2.x, ay = dv * x2.y;
    int j = 0;
    for (; j + 4 <= c; j += 4) {
      int s0 = es[j], s1 = es[j + 1], s2 = es[j + 2], s3 = es[j + 3];
      float d0 = dinv[s0], d1 = dinv[s1], d2 = dinv[s2], d3 = dinv[s3];
      float2 v0 = *(const float2*)&in[(size_t)s0 * 128 + 2 * lane];
      float2 v1 = *(const float2*)&in[(size_t)s1 * 128 + 2 * lane];
      float2 v2 = *(const float2*)&in[(size_t)s2 * 128 + 2 * lane];
      float2 v3 = *(const float2*)&in[(size_t)s3 * 128 + 2 * lane];
      ax = fmaf(d0, v0.x, ax); ay = fmaf(d0, v0.y, ay);
      ax = fmaf(d1, v1.x, ax); ay = fmaf(d1, v1.y, ay);
      ax = fmaf(d2, v2.x, ax); ay = fmaf(d2, v2.y, ay);
      ax = fmaf(d3, v3.x, ax); ay = fmaf(d3, v3.y, ay);
    }
    for (; j < c; j++) {
      int sj = es[j];
      float dj = dinv[sj];
      float2 v = *(const float2*)&in[(size_t)sj * 128 + 2 * lane];
      ax = fmaf(dj, v.x, ax); ay = fmaf(dj, v.y, ay);
    }
    ax *= dv; ay *= dv;
    if constexpr (NFO == 128) {
      float o0 = 0.f, o1 = 0.f;
      #pragma unroll
      for (int kk = 0; kk < 64; kk++) {
        float xa = __shfl(ax, kk);
        float xb = __shfl(ay, kk);
        float2 wA = *(const float2*)&Wl[(2 * kk) * 128 + 2 * lane];
        float2 wB = *(const float2*)&Wl[(2 * kk + 1) * 128 + 2 * lane];
        o0 = fmaf(xa, wA.x, o0); o1 = fmaf(xa, wA.y, o1);
        o0 = fmaf(xb, wB.x, o0); o1 = fmaf(xb, wB.y, o1);
      }
      float2 bb = *(const float2*)&bias[2 * lane];
      float r0 = o0 + bb.x, r1 = o1 + bb.y;
      if (RELU) { r0 = fmaxf(r0, 0.f); r1 = fmaxf(r1, 0.f); }
      *(float2*)&out[(size_t)node * 128 + 2 * lane] = make_float2(r0, r1);
    } else {
      float o0 = 0.f;
      #pragma unroll
      for (int kk = 0; kk < 64; kk++) {
        float xa = __shfl(ax, kk);
        float xb = __shfl(ay, kk);
        o0 = fmaf(xa, Wl[(2 * kk) * NFO + lane], o0);
        o0 = fmaf(xb, Wl[(2 * kk + 1) * NFO + lane], o0);
      }
      float r0 = o0 + bias[lane];
      if (RELU) r0 = fmaxf(r0, 0.f);
      out[(size_t)node * NFO + lane] = r0;
    }
  }
}

// ---------------------------------------------------------------------------

extern "C" void kernel_launch(void* const* d_in, const int* in_sizes, int n_in,
                              void* d_out, int out_size, void* d_ws, size_t ws_size,
                              hipStream_t stream) {
  const float* x  = (const float*)d_in[0];
  const int*   ei = (const int*)d_in[1];
  const float* W1 = (const float*)d_in[2];
  const float* b1 = (const float*)d_in[3];
  const float* W2 = (const float*)d_in[4];
  const float* b2 = (const float*)d_in[5];
  const float* W3 = (const float*)d_in[6];
  const float* b3 = (const float*)d_in[7];

  const int N = in_sizes[0] / 128;
  const int E = in_sizes[1] / 2;
  const int* src = ei;
  const int* dst = ei + E;

  char* ws = (char*)d_ws;
  size_t off = 0;
  auto alloc = [&](size_t bytes) -> void* {
    void* p = ws + off;
    off = (off + bytes + 255) & ~(size_t)255;
    return p;
  };
  int*   cnt      = (int*)alloc((size_t)N * 4);
  int*   fillPos  = (int*)alloc((size_t)N * 4);
  int*   rowStart = (int*)alloc((size_t)N * 4);
  float* dinv     = (float*)alloc((size_t)N * 4);
  int*   bsum     = (int*)alloc(512);
  int*   eSrc     = (int*)alloc((size_t)E * 4);
  unsigned* sU    = (unsigned*)alloc((size_t)N * 64 * 4);  // s rows, bf16, 256B
  unsigned* tB    = (unsigned*)alloc((size_t)N * 64 * 4);  // t rows, bf16, 256B
  const bool fast = (ws_size >= off);                       // ~59.2 MB

  float* y    = (float*)d_out;          // [N,64]
  float* out1 = y + (size_t)N * 64;     // [N,128]
  float* out2 = out1 + (size_t)N * 128; // [N,128]

  // ---- CSR build ----
  k_zero<<<(N + 255) / 256, 256, 0, stream>>>(cnt, fillPos, N);
  k_deg<<<2048, 256, 0, stream>>>(dst, cnt, E);
  k_dinv<<<(N + 255) / 256, 256, 0, stream>>>(cnt, dinv, N);
  int nChunks = (N + 1023) / 1024;
  k_scan1<<<nChunks, 256, 0, stream>>>(cnt, rowStart, bsum, N);
  k_scan2<<<1, 128, 0, stream>>>(bsum, nChunks);
  k_scan3<<<(N + 255) / 256, 256, 0, stream>>>(rowStart, bsum, N);
  k_fill<<<2048, 256, 0, stream>>>(src, dst, rowStart, fillPos, eSrc, E);

  if (fast) {
    const int aggBlocks = (N + 3) / 4;
    k_scale<<<(N * 16 + 255) / 256, 256, 0, stream>>>(x, dinv, (uint4*)sU, N * 16);
    // L1
    k_agg<<<aggBlocks, 256, 0, stream>>>(sU, dinv, eSrc, rowStart, cnt, tB, N);
    k_gemmT<128, true, true><<<1024, 512, 0, stream>>>(tB, W1, b1, dinv, out1, sU, N);
    // L2
    k_agg<<<aggBlocks, 256, 0, stream>>>(sU, dinv, eSrc, rowStart, cnt, tB, N);
    k_gemmT<128, true, true><<<1024, 512, 0, stream>>>(tB, W2, b2, dinv, out2, sU, N);
    // L3
    k_agg<<<aggBlocks, 256, 0, stream>>>(sU, dinv, eSrc, rowStart, cnt, tB, N);
    k_gemmT<64, false, false><<<1024, 512, 0, stream>>>(tB, W3, b3, dinv, y, nullptr, N);
  } else {
    k_layer_f32<128, true ><<<1024, 512, 0, stream>>>(x,    W1, b1, dinv, eSrc, rowStart, cnt, out1, N);
    k_layer_f32<128, true ><<<1024, 512, 0, stream>>>(out1, W2, b2, dinv, eSrc, rowStart, cnt, out2, N);
    k_layer_f32<64,  false><<<1024, 512, 0, stream>>>(out2, W3, b3, dinv, eSrc, rowStart, cnt, y,    N);
  }
}

// Round 22
// 454.235 us; speedup vs baseline: 11.9413x; 2.0076x over previous
//
#include <hip/hip_runtime.h>
#include <math.h>

// ---------------------------------------------------------------------------
// 3-layer GCN on MI355X, SPLIT aggregate / MFMA-GEMM form (round-22 = r21
// with the compile error fixed: dead trowAt loop removed).
//   out = relu( (A_hat @ in) @ W + b ),  A_hat = D^-1/2 (A+I) D^-1/2
//   k_agg  : depth-4 exact-byte bf16 gathers, no LDS, 32 waves/CU (solved;
//            r16/r20 evidence). Writes t = bf16(dinv * gathered sum).
//   k_gemmM: mfma_f32_16x16x32_bf16. Per wave: 16 nodes x NFO cols.
//            A = t rows (bf16, global); B = W bf16 transposed in LDS
//            [col][k] with 8B-granule XOR swizzle (h ^= col&7). Replaces
//            r20's shfl-GEMM (200us, VALU/DS-bound). Epilogue fuses
//            bias/relu/out-store + sNext bf16 prescale pack (shfl_xor(1)).
// Fragment layouts: C/D col=lane&15,row=(lane>>4)*4+reg (HW-verified m89);
// A lane: row=l&15, k=4*(l>>4)+j and +16 (two 4-k groups); B symmetric.
// CSR over dst rebuilt on-device every call.
// ---------------------------------------------------------------------------

typedef __attribute__((ext_vector_type(8))) short bfrag8;
typedef __attribute__((ext_vector_type(4))) float ffrag4;

__device__ __forceinline__ unsigned short f2bf(float f) {
  unsigned u = __float_as_uint(f);
  return (unsigned short)((u + 0x7FFFu + ((u >> 16) & 1u)) >> 16);
}
__device__ __forceinline__ float bfLo(unsigned v) { return __uint_as_float(v << 16); }
__device__ __forceinline__ float bfHi(unsigned v) { return __uint_as_float(v & 0xFFFF0000u); }

// ------------------------------- CSR build ---------------------------------

__global__ __launch_bounds__(256) void k_zero(int* __restrict__ cnt,
                                              int* __restrict__ fillPos, int n) {
  int i = blockIdx.x * blockDim.x + threadIdx.x;
  if (i < n) { cnt[i] = 0; fillPos[i] = 0; }
}

__global__ __launch_bounds__(256) void k_deg(const int* __restrict__ dst,
                                             int* __restrict__ cnt, int E) {
  int i = blockIdx.x * blockDim.x + threadIdx.x;
  int stride = gridDim.x * blockDim.x;
  for (; i < E; i += stride) atomicAdd(&cnt[dst[i]], 1);
}

__global__ __launch_bounds__(256) void k_dinv(const int* __restrict__ cnt,
                                              float* __restrict__ dinv, int n) {
  int i = blockIdx.x * blockDim.x + threadIdx.x;
  if (i < n) dinv[i] = rsqrtf(1.0f + (float)cnt[i]);
}

__global__ __launch_bounds__(256) void k_scan1(const int* __restrict__ cnt,
                                               int* __restrict__ exc,
                                               int* __restrict__ bsum, int n) {
  __shared__ int lds[256];
  int t = threadIdx.x;
  int base = blockIdx.x * 1024 + t * 4;
  int v0 = (base + 0 < n) ? cnt[base + 0] : 0;
  int v1 = (base + 1 < n) ? cnt[base + 1] : 0;
  int v2 = (base + 2 < n) ? cnt[base + 2] : 0;
  int v3 = (base + 3 < n) ? cnt[base + 3] : 0;
  int sum = v0 + v1 + v2 + v3;
  lds[t] = sum;
  __syncthreads();
  for (int off = 1; off < 256; off <<= 1) {
    int val = lds[t];
    if (t >= off) val += lds[t - off];
    __syncthreads();
    lds[t] = val;
    __syncthreads();
  }
  int ex = lds[t] - sum;
  if (base + 0 < n) exc[base + 0] = ex;
  ex += v0;
  if (base + 1 < n) exc[base + 1] = ex;
  ex += v1;
  if (base + 2 < n) exc[base + 2] = ex;
  ex += v2;
  if (base + 3 < n) exc[base + 3] = ex;
  if (t == 255) bsum[blockIdx.x] = lds[255];
}

__global__ __launch_bounds__(128) void k_scan2(int* __restrict__ bsum, int nb) {
  __shared__ int lds[128];
  int t = threadIdx.x;
  int v = (t < nb) ? bsum[t] : 0;
  lds[t] = v;
  __syncthreads();
  for (int off = 1; off < 128; off <<= 1) {
    int val = lds[t];
    if (t >= off) val += lds[t - off];
    __syncthreads();
    lds[t] = val;
    __syncthreads();
  }
  if (t < nb) bsum[t] = lds[t] - v;
}

__global__ __launch_bounds__(256) void k_scan3(int* __restrict__ exc,
                                               const int* __restrict__ bsum, int n) {
  int i = blockIdx.x * blockDim.x + threadIdx.x;
  if (i < n) exc[i] += bsum[i >> 10];
}

__global__ __launch_bounds__(256) void k_fill(const int* __restrict__ src,
                                              const int* __restrict__ dst,
                                              const int* __restrict__ rowStart,
                                              int* __restrict__ fillPos,
                                              int* __restrict__ eSrc, int E) {
  int i = blockIdx.x * blockDim.x + threadIdx.x;
  int stride = gridDim.x * blockDim.x;
  for (; i < E; i += stride) {
    int d = dst[i];
    int p = rowStart[d] + atomicAdd(&fillPos[d], 1);
    eSrc[p] = src[i];
  }
}

// ---------------- bf16 prescale: s = bf16(dinv * h), 256B rows -------------

__global__ __launch_bounds__(256) void k_scale(const float* __restrict__ h,
                                               const float* __restrict__ dinv,
                                               uint4* __restrict__ s4, int nQuads) {
  int i = blockIdx.x * blockDim.x + threadIdx.x;
  int stride = gridDim.x * blockDim.x;
  for (; i < nQuads; i += stride) {
    int row = i >> 4;
    int q = i & 15;
    float dv = dinv[row];
    const float4* hp = (const float4*)&h[(size_t)row * 128 + 8 * q];
    float4 a = hp[0], b = hp[1];
    uint4 o;
    o.x = (unsigned)f2bf(dv * a.x) | ((unsigned)f2bf(dv * a.y) << 16);
    o.y = (unsigned)f2bf(dv * a.z) | ((unsigned)f2bf(dv * a.w) << 16);
    o.z = (unsigned)f2bf(dv * b.x) | ((unsigned)f2bf(dv * b.y) << 16);
    o.w = (unsigned)f2bf(dv * b.z) | ((unsigned)f2bf(dv * b.w) << 16);
    s4[i] = o;
  }
}

// ---- k_agg: gather-only, depth-4 pairs, no LDS, 32 waves/CU ---------------
__global__ __launch_bounds__(256, 8) void k_agg(const unsigned* __restrict__ sU,
                                                const float* __restrict__ dinv,
                                                const int* __restrict__ eSrc,
                                                const int* __restrict__ rowStart,
                                                const int* __restrict__ cnt,
                                                unsigned* __restrict__ tB, int n) {
  const int wid = threadIdx.x >> 6, lane = threadIdx.x & 63;
  const int half = lane >> 5, sl = lane & 31;
  for (int node = blockIdx.x * 4 + wid; node < n; node += gridDim.x * 4) {
    const int st = rowStart[node], c = cnt[node];
    const int* es = eSrc + st;
    const float dv = dinv[node];
    uint2 vs = *(const uint2*)&sU[(size_t)node * 64 + 2 * sl];  // self row
    float a0, a1, a2, a3;
    if (half == 0) {
      a0 = bfLo(vs.x); a1 = bfHi(vs.x); a2 = bfLo(vs.y); a3 = bfHi(vs.y);
    } else {
      a0 = a1 = a2 = a3 = 0.f;
    }
    const int cl = c < 64 ? c : 64;
    int myIdx = (lane < cl) ? es[lane] : 0;
    int j = 0;
    for (; j + 8 <= cl; j += 8) {  // 4 independent pair-loads = 8 edges
      int iA0 = __shfl(myIdx, j + 0), iB0 = __shfl(myIdx, j + 1);
      int iA1 = __shfl(myIdx, j + 2), iB1 = __shfl(myIdx, j + 3);
      int iA2 = __shfl(myIdx, j + 4), iB2 = __shfl(myIdx, j + 5);
      int iA3 = __shfl(myIdx, j + 6), iB3 = __shfl(myIdx, j + 7);
      int x0 = half ? iB0 : iA0;
      int x1 = half ? iB1 : iA1;
      int x2 = half ? iB2 : iA2;
      int x3 = half ? iB3 : iA3;
      uint2 v0 = *(const uint2*)&sU[(size_t)x0 * 64 + 2 * sl];
      uint2 v1 = *(const uint2*)&sU[(size_t)x1 * 64 + 2 * sl];
      uint2 v2 = *(const uint2*)&sU[(size_t)x2 * 64 + 2 * sl];
      uint2 v3 = *(const uint2*)&sU[(size_t)x3 * 64 + 2 * sl];
      a0 += bfLo(v0.x); a1 += bfHi(v0.x); a2 += bfLo(v0.y); a3 += bfHi(v0.y);
      a0 += bfLo(v1.x); a1 += bfHi(v1.x); a2 += bfLo(v1.y); a3 += bfHi(v1.y);
      a0 += bfLo(v2.x); a1 += bfHi(v2.x); a2 += bfLo(v2.y); a3 += bfHi(v2.y);
      a0 += bfLo(v3.x); a1 += bfHi(v3.x); a2 += bfLo(v3.y); a3 += bfHi(v3.y);
    }
    for (; j < c; j += 2) {  // pair tail (odd c and c>64)
      int iA = (j < cl) ? __shfl(myIdx, j) : es[j];
      int hasB = (j + 1 < c);
      int iB = hasB ? ((j + 1 < cl) ? __shfl(myIdx, j + 1) : es[j + 1]) : iA;
      int x = half ? iB : iA;
      uint2 v = *(const uint2*)&sU[(size_t)x * 64 + 2 * sl];
      if (half && !hasB) { v.x = 0u; v.y = 0u; }
      a0 += bfLo(v.x); a1 += bfHi(v.x); a2 += bfLo(v.y); a3 += bfHi(v.y);
    }
    a0 += __shfl_xor(a0, 32);
    a1 += __shfl_xor(a1, 32);
    a2 += __shfl_xor(a2, 32);
    a3 += __shfl_xor(a3, 32);
    if (half == 0) {  // pack & store t row (256B, 32 lanes x uint2)
      uint2 o;
      o.x = (unsigned)f2bf(dv * a0) | ((unsigned)f2bf(dv * a1) << 16);
      o.y = (unsigned)f2bf(dv * a2) | ((unsigned)f2bf(dv * a3) << 16);
      *(uint2*)&tB[(size_t)node * 64 + 2 * sl] = o;
    }
  }
}

// ---- k_gemmM: MFMA GEMM. t (bf16 rows) @ W + b -> out fp32 [+ sNext] ------
// Wave tile: 16 nodes x NFO cols; K = 128 in 4 chunks of 32.
// Wt LDS layout: [col][k] bf16, 8B granule h stored at h ^ (col&7).
template <int NFO, bool RELU, bool WRITE_S>
__global__ __launch_bounds__(256) void k_gemmM(const unsigned* __restrict__ tB,
                                               const float* __restrict__ W,
                                               const float* __restrict__ bias,
                                               const float* __restrict__ dinv,
                                               float* __restrict__ out,
                                               unsigned* __restrict__ sNext, int n) {
  __shared__ unsigned short Wt[NFO * 128];  // NFO cols x 128 k (swizzled)
  for (int t = threadIdx.x; t < 128 * NFO; t += 256) {
    int k = t / NFO, c = t % NFO;  // W row-major [k][col]
    int hs = (k >> 2) ^ (c & 7);   // 8B granule swizzle
    Wt[c * 128 + hs * 4 + (k & 3)] = f2bf(W[t]);
  }
  __syncthreads();
  const int wid = threadIdx.x >> 6, lane = threadIdx.x & 63;
  const int r16 = lane & 15;  // A-row(node) / B,C-col within tile
  const int q4 = lane >> 4;   // quarter
  const int NT = NFO / 16;
  for (int node0 = (blockIdx.x * 4 + wid) * 16; node0 < n;
       node0 += gridDim.x * 4 * 16) {
    if (node0 + 16 <= n) {
      // ---- A fragments: 16 t-rows; lane: row r16, k=32kc+4q4+j (+16) ----
      const unsigned* trow = tB + (size_t)(node0 + r16) * 64;
      union { uint2 u2[2]; bfrag8 v; } Af[4];
      #pragma unroll
      for (int kc = 0; kc < 4; kc++) {
        Af[kc].u2[0] = *(const uint2*)&trow[kc * 16 + 2 * q4];      // k..k+3
        Af[kc].u2[1] = *(const uint2*)&trow[kc * 16 + 8 + 2 * q4];  // k+16..+19
      }
      float dvr[4];
      if (WRITE_S) {
        #pragma unroll
        for (int r = 0; r < 4; r++) dvr[r] = dinv[node0 + q4 * 4 + r];
      }
      #pragma unroll
      for (int ct = 0; ct < NT; ct++) {
        const int col = 16 * ct + r16;
        const int cbase = col * 128;
        const int csw = col & 7;
        ffrag4 acc = {0.f, 0.f, 0.f, 0.f};
        #pragma unroll
        for (int kc = 0; kc < 4; kc++) {
          int h0 = kc * 8 + q4;
          union { uint2 u2[2]; bfrag8 v; } Bf;
          Bf.u2[0] = *(const uint2*)&Wt[cbase + ((h0) ^ csw) * 4];
          Bf.u2[1] = *(const uint2*)&Wt[cbase + ((h0 + 4) ^ csw) * 4];
          acc = __builtin_amdgcn_mfma_f32_16x16x32_bf16(Af[kc].v, Bf.v, acc,
                                                        0, 0, 0);
        }
        float bb = bias[col];
        #pragma unroll
        for (int r = 0; r < 4; r++) {
          int node = node0 + q4 * 4 + r;
          float v = acc[r] + bb;
          if (RELU) v = fmaxf(v, 0.f);
          out[(size_t)node * NFO + col] = v;
          if (WRITE_S) {
            float sv = dvr[r] * v;
            float pv = __shfl_xor(sv, 1);  // partner col (col^1)
            if ((lane & 1) == 0)
              sNext[(size_t)node * 64 + (col >> 1)] =
                  (unsigned)f2bf(sv) | ((unsigned)f2bf(pv) << 16);
          }
        }
      }
    } else {
      // tail (<16 nodes): direct scalar recompute (N%16==0 here; safety only)
      for (int idx = lane; idx < 16 * NFO; idx += 64) {
        int node = node0 + idx / NFO;
        if (node < n) {
          int col = idx % NFO;
          float acc = 0.f;
          for (int k = 0; k < 128; k++) {
            unsigned tw = tB[(size_t)node * 64 + (k >> 1)];
            float tv = (k & 1) ? bfHi(tw) : bfLo(tw);
            int hs = (k >> 2) ^ (col & 7);
            unsigned short wv = Wt[col * 128 + hs * 4 + (k & 3)];
            acc = fmaf(tv, __uint_as_float(((unsigned)wv) << 16), acc);
          }
          float v = acc + bias[col];
          if (RELU) v = fmaxf(v, 0.f);
          out[(size_t)node * NFO + col] = v;
          if (WRITE_S) {
            unsigned short* sh = (unsigned short*)sNext;
            sh[(size_t)node * 128 + col] = f2bf(dinv[node] * v);
          }
        }
      }
    }
  }
}

// --------------------- fp32 fused kernel (ws-fallback) ---------------------

template <int NFO, bool RELU>
__global__ __launch_bounds__(512) void k_layer_f32(const float* __restrict__ in,
                                                   const float* __restrict__ W,
                                                   const float* __restrict__ bias,
                                                   const float* __restrict__ dinv,
                                                   const int* __restrict__ eSrc,
                                                   const int* __restrict__ rowStart,
                                                   const int* __restrict__ cnt,
                                                   float* __restrict__ out, int n) {
  __shared__ float Wl[128 * NFO];
  for (int t = threadIdx.x; t < 128 * NFO; t += 512) Wl[t] = W[t];
  __syncthreads();
  const int wid = threadIdx.x >> 6, lane = threadIdx.x & 63;
  for (int node = blockIdx.x * 8 + wid; node < n; node += gridDim.x * 8) {
    const int s = rowStart[node], c = cnt[node];
    const int* es = eSrc + s;
    const float dv = dinv[node];
    float2 x2 = *(const float2*)&in[(size_t)node * 128 + 2 * lane];
    float ax = dv * x2.x, ay = dv * x2.y;
    int j = 0;
    for (; j + 4 <= c; j += 4) {
      int s0 = es[j], s1 = es[j + 1], s2 = es[j + 2], s3 = es[j + 3];
      float d0 = dinv[s0], d1 = dinv[s1], d2 = dinv[s2], d3 = dinv[s3];
      float2 v0 = *(const float2*)&in[(size_t)s0 * 128 + 2 * lane];
      float2 v1 = *(const float2*)&in[(size_t)s1 * 128 + 2 * lane];
      float2 v2 = *(const float2*)&in[(size_t)s2 * 128 + 2 * lane];
      float2 v3 = *(const float2*)&in[(size_t)s3 * 128 + 2 * lane];
      ax = fmaf(d0, v0.x, ax); ay = fmaf(d0, v0.y, ay);
      ax = fmaf(d1, v1.x, ax); ay = fmaf(d1, v1.y, ay);
      ax = fmaf(d2, v2.x, ax); ay = fmaf(d2, v2.y, ay);
      ax = fmaf(d3, v3.x, ax); ay = fmaf(d3, v3.y, ay);
    }
    for (; j < c; j++) {
      int sj = es[j];
      float dj = dinv[sj];
      float2 v = *(const float2*)&in[(size_t)sj * 128 + 2 * lane];
      ax = fmaf(dj, v.x, ax); ay = fmaf(dj, v.y, ay);
    }
    ax *= dv; ay *= dv;
    if constexpr (NFO == 128) {
      float o0 = 0.f, o1 = 0.f;
      #pragma unroll 4
      for (int kk = 0; kk < 64; kk++) {
        float xa = __shfl(ax, kk);
        float xb = __shfl(ay, kk);
        float2 wA = *(const float2*)&Wl[(2 * kk) * 128 + 2 * lane];
        float2 wB = *(const float2*)&Wl[(2 * kk + 1) * 128 + 2 * lane];
        o0 = fmaf(xa, wA.x, o0); o1 = fmaf(xa, wA.y, o1);
        o0 = fmaf(xb, wB.x, o0); o1 = fmaf(xb, wB.y, o1);
      }
      float2 bb = *(const float2*)&bias[2 * lane];
      float r0 = o0 + bb.x, r1 = o1 + bb.y;
      if (RELU) { r0 = fmaxf(r0, 0.f); r1 = fmaxf(r1, 0.f); }
      *(float2*)&out[(size_t)node * 128 + 2 * lane] = make_float2(r0, r1);
    } else {
      float o0 = 0.f;
      #pragma unroll 4
      for (int kk = 0; kk < 64; kk++) {
        float xa = __shfl(ax, kk);
        float xb = __shfl(ay, kk);
        o0 = fmaf(xa, Wl[(2 * kk) * NFO + lane], o0);
        o0 = fmaf(xb, Wl[(2 * kk + 1) * NFO + lane], o0);
      }
      float r0 = o0 + bias[lane];
      if (RELU) r0 = fmaxf(r0, 0.f);
      out[(size_t)node * NFO + lane] = r0;
    }
  }
}

// ---------------------------------------------------------------------------

extern "C" void kernel_launch(void* const* d_in, const int* in_sizes, int n_in,
                              void* d_out, int out_size, void* d_ws, size_t ws_size,
                              hipStream_t stream) {
  const float* x  = (const float*)d_in[0];
  const int*   ei = (const int*)d_in[1];
  const float* W1 = (const float*)d_in[2];
  const float* b1 = (const float*)d_in[3];
  const float* W2 = (const float*)d_in[4];
  const float* b2 = (const float*)d_in[5];
  const float* W3 = (const float*)d_in[6];
  const float* b3 = (const float*)d_in[7];

  const int N = in_sizes[0] / 128;
  const int E = in_sizes[1] / 2;
  const int* src = ei;
  const int* dst = ei + E;

  char* ws = (char*)d_ws;
  size_t off = 0;
  auto alloc = [&](size_t bytes) -> void* {
    void* p = ws + off;
    off = (off + bytes + 255) & ~(size_t)255;
    return p;
  };
  int*   cnt      = (int*)alloc((size_t)N * 4);
  int*   fillPos  = (int*)alloc((size_t)N * 4);
  int*   rowStart = (int*)alloc((size_t)N * 4);
  float* dinv     = (float*)alloc((size_t)N * 4);
  int*   bsum     = (int*)alloc(512);
  int*   eSrc     = (int*)alloc((size_t)E * 4);
  unsigned* sU    = (unsigned*)alloc((size_t)N * 64 * 4);  // s rows, bf16, 256B
  unsigned* tB    = (unsigned*)alloc((size_t)N * 64 * 4);  // t rows, bf16, 256B
  const bool fast = (ws_size >= off);                       // ~59.2 MB

  float* y    = (float*)d_out;          // [N,64]
  float* out1 = y + (size_t)N * 64;     // [N,128]
  float* out2 = out1 + (size_t)N * 128; // [N,128]

  // ---- CSR build ----
  k_zero<<<(N + 255) / 256, 256, 0, stream>>>(cnt, fillPos, N);
  k_deg<<<2048, 256, 0, stream>>>(dst, cnt, E);
  k_dinv<<<(N + 255) / 256, 256, 0, stream>>>(cnt, dinv, N);
  int nChunks = (N + 1023) / 1024;
  k_scan1<<<nChunks, 256, 0, stream>>>(cnt, rowStart, bsum, N);
  k_scan2<<<1, 128, 0, stream>>>(bsum, nChunks);
  k_scan3<<<(N + 255) / 256, 256, 0, stream>>>(rowStart, bsum, N);
  k_fill<<<2048, 256, 0, stream>>>(src, dst, rowStart, fillPos, eSrc, E);

  if (fast) {
    const int aggBlocks = (N + 3) / 4;
    const int tiles = (N + 15) / 16;
    const int gmBlocks = (tiles + 3) / 4;
    k_scale<<<(N * 16 + 255) / 256, 256, 0, stream>>>(x, dinv, (uint4*)sU, N * 16);
    // L1
    k_agg<<<aggBlocks, 256, 0, stream>>>(sU, dinv, eSrc, rowStart, cnt, tB, N);
    k_gemmM<128, true, true><<<gmBlocks, 256, 0, stream>>>(tB, W1, b1, dinv, out1, sU, N);
    // L2
    k_agg<<<aggBlocks, 256, 0, stream>>>(sU, dinv, eSrc, rowStart, cnt, tB, N);
    k_gemmM<128, true, true><<<gmBlocks, 256, 0, stream>>>(tB, W2, b2, dinv, out2, sU, N);
    // L3
    k_agg<<<aggBlocks, 256, 0, stream>>>(sU, dinv, eSrc, rowStart, cnt, tB, N);
    k_gemmM<64, false, false><<<gmBlocks, 256, 0, stream>>>(tB, W3, b3, dinv, y, nullptr, N);
  } else {
    k_layer_f32<128, true ><<<1024, 512, 0, stream>>>(x,    W1, b1, dinv, eSrc, rowStart, cnt, out1, N);
    k_layer_f32<128, true ><<<1024, 512, 0, stream>>>(out1, W2, b2, dinv, eSrc, rowStart, cnt, out2, N);
    k_layer_f32<64,  false><<<1024, 512, 0, stream>>>(out2, W3, b3, dinv, eSrc, rowStart, cnt, y,    N);
  }
}

// Round 23
// 439.050 us; speedup vs baseline: 12.3543x; 1.0346x over previous
//
#include <hip/hip_runtime.h>
#include <math.h>

// ---------------------------------------------------------------------------
// 3-layer GCN on MI355X, SPLIT aggregate / MFMA-GEMM form (round-23).
//   out = relu( (A_hat @ in) @ W + b ),  A_hat = D^-1/2 (A+I) D^-1/2
//   k_agg  : depth-4 exact-byte bf16 gathers, no LDS, 32 waves/CU.
//   k_gemmM: mfma_f32_16x16x32_bf16, W bf16 swizzled in LDS (r22: 912->454us,
//            gemm+agg both out of top-5).
//   k_fill8: NEW -- XCD-range-partitioned CSR slot fill. r22 counters: old
//            k_fill wrote 107.7MB HBM for a 6.4MB eSrc (random 4B scatters
//            -> 64B line ping-pong across 8 non-coherent L2s) at 0.97 TB/s
//            = 122us. Partition dst into 8 ranges; blocks with blockIdx&7==r
//            process only range r (round-robin block->XCD heuristic) ->
//            writes+atomics stay XCD-local, writeback ~6.4MB. Edge list is
//            re-read 8x but linear/L3-resident (~15us).
// CSR over dst rebuilt on-device every call.
// ---------------------------------------------------------------------------

typedef __attribute__((ext_vector_type(8))) short bfrag8;
typedef __attribute__((ext_vector_type(4))) float ffrag4;

__device__ __forceinline__ unsigned short f2bf(float f) {
  unsigned u = __float_as_uint(f);
  return (unsigned short)((u + 0x7FFFu + ((u >> 16) & 1u)) >> 16);
}
__device__ __forceinline__ float bfLo(unsigned v) { return __uint_as_float(v << 16); }
__device__ __forceinline__ float bfHi(unsigned v) { return __uint_as_float(v & 0xFFFF0000u); }

// ------------------------------- CSR build ---------------------------------

__global__ __launch_bounds__(256) void k_zero(int* __restrict__ cnt,
                                              int* __restrict__ fillPos, int n) {
  int i = blockIdx.x * blockDim.x + threadIdx.x;
  if (i < n) { cnt[i] = 0; fillPos[i] = 0; }
}

__global__ __launch_bounds__(256) void k_deg(const int* __restrict__ dst,
                                             int* __restrict__ cnt, int E) {
  int i = blockIdx.x * blockDim.x + threadIdx.x;
  int stride = gridDim.x * blockDim.x;
  for (; i < E; i += stride) atomicAdd(&cnt[dst[i]], 1);
}

__global__ __launch_bounds__(256) void k_dinv(const int* __restrict__ cnt,
                                              float* __restrict__ dinv, int n) {
  int i = blockIdx.x * blockDim.x + threadIdx.x;
  if (i < n) dinv[i] = rsqrtf(1.0f + (float)cnt[i]);
}

__global__ __launch_bounds__(256) void k_scan1(const int* __restrict__ cnt,
                                               int* __restrict__ exc,
                                               int* __restrict__ bsum, int n) {
  __shared__ int lds[256];
  int t = threadIdx.x;
  int base = blockIdx.x * 1024 + t * 4;
  int v0 = (base + 0 < n) ? cnt[base + 0] : 0;
  int v1 = (base + 1 < n) ? cnt[base + 1] : 0;
  int v2 = (base + 2 < n) ? cnt[base + 2] : 0;
  int v3 = (base + 3 < n) ? cnt[base + 3] : 0;
  int sum = v0 + v1 + v2 + v3;
  lds[t] = sum;
  __syncthreads();
  for (int off = 1; off < 256; off <<= 1) {
    int val = lds[t];
    if (t >= off) val += lds[t - off];
    __syncthreads();
    lds[t] = val;
    __syncthreads();
  }
  int ex = lds[t] - sum;
  if (base + 0 < n) exc[base + 0] = ex;
  ex += v0;
  if (base + 1 < n) exc[base + 1] = ex;
  ex += v1;
  if (base + 2 < n) exc[base + 2] = ex;
  ex += v2;
  if (base + 3 < n) exc[base + 3] = ex;
  if (t == 255) bsum[blockIdx.x] = lds[255];
}

__global__ __launch_bounds__(128) void k_scan2(int* __restrict__ bsum, int nb) {
  __shared__ int lds[128];
  int t = threadIdx.x;
  int v = (t < nb) ? bsum[t] : 0;
  lds[t] = v;
  __syncthreads();
  for (int off = 1; off < 128; off <<= 1) {
    int val = lds[t];
    if (t >= off) val += lds[t - off];
    __syncthreads();
    lds[t] = val;
    __syncthreads();
  }
  if (t < nb) bsum[t] = lds[t] - v;
}

__global__ __launch_bounds__(256) void k_scan3(int* __restrict__ exc,
                                               const int* __restrict__ bsum, int n) {
  int i = blockIdx.x * blockDim.x + threadIdx.x;
  if (i < n) exc[i] += bsum[i >> 10];
}

// XCD-range-partitioned slot fill: blocks with (blockIdx&7)==r handle dst in
// [r*rsize, (r+1)*rsize). Writes/atomics stay XCD-local (round-robin block
// dispatch heuristic); correctness independent of the actual mapping.
__global__ __launch_bounds__(256) void k_fill8(const int* __restrict__ src,
                                               const int* __restrict__ dst,
                                               const int* __restrict__ rowStart,
                                               int* __restrict__ fillPos,
                                               int* __restrict__ eSrc,
                                               int E, int rsize) {
  const int range = blockIdx.x & 7;
  const int sub = blockIdx.x >> 3;
  const int nSub = gridDim.x >> 3;
  const int lo = range * rsize, hi = lo + rsize;
  int i = sub * blockDim.x + threadIdx.x;
  const int stride = nSub * blockDim.x;
  for (; i < E; i += stride) {
    int d = dst[i];
    if (d >= lo && d < hi) {
      int p = rowStart[d] + atomicAdd(&fillPos[d], 1);
      eSrc[p] = src[i];
    }
  }
}

// ---------------- bf16 prescale: s = bf16(dinv * h), 256B rows -------------

__global__ __launch_bounds__(256) void k_scale(const float* __restrict__ h,
                                               const float* __restrict__ dinv,
                                               uint4* __restrict__ s4, int nQuads) {
  int i = blockIdx.x * blockDim.x + threadIdx.x;
  int stride = gridDim.x * blockDim.x;
  for (; i < nQuads; i += stride) {
    int row = i >> 4;
    int q = i & 15;
    float dv = dinv[row];
    const float4* hp = (const float4*)&h[(size_t)row * 128 + 8 * q];
    float4 a = hp[0], b = hp[1];
    uint4 o;
    o.x = (unsigned)f2bf(dv * a.x) | ((unsigned)f2bf(dv * a.y) << 16);
    o.y = (unsigned)f2bf(dv * a.z) | ((unsigned)f2bf(dv * a.w) << 16);
    o.z = (unsigned)f2bf(dv * b.x) | ((unsigned)f2bf(dv * b.y) << 16);
    o.w = (unsigned)f2bf(dv * b.z) | ((unsigned)f2bf(dv * b.w) << 16);
    s4[i] = o;
  }
}

// ---- k_agg: gather-only, depth-4 pairs, no LDS, 32 waves/CU ---------------
__global__ __launch_bounds__(256, 8) void k_agg(const unsigned* __restrict__ sU,
                                                const float* __restrict__ dinv,
                                                const int* __restrict__ eSrc,
                                                const int* __restrict__ rowStart,
                                                const int* __restrict__ cnt,
                                                unsigned* __restrict__ tB, int n) {
  const int wid = threadIdx.x >> 6, lane = threadIdx.x & 63;
  const int half = lane >> 5, sl = lane & 31;
  for (int node = blockIdx.x * 4 + wid; node < n; node += gridDim.x * 4) {
    const int st = rowStart[node], c = cnt[node];
    const int* es = eSrc + st;
    const float dv = dinv[node];
    uint2 vs = *(const uint2*)&sU[(size_t)node * 64 + 2 * sl];  // self row
    float a0, a1, a2, a3;
    if (half == 0) {
      a0 = bfLo(vs.x); a1 = bfHi(vs.x); a2 = bfLo(vs.y); a3 = bfHi(vs.y);
    } else {
      a0 = a1 = a2 = a3 = 0.f;
    }
    const int cl = c < 64 ? c : 64;
    int myIdx = (lane < cl) ? es[lane] : 0;
    int j = 0;
    for (; j + 8 <= cl; j += 8) {  // 4 independent pair-loads = 8 edges
      int iA0 = __shfl(myIdx, j + 0), iB0 = __shfl(myIdx, j + 1);
      int iA1 = __shfl(myIdx, j + 2), iB1 = __shfl(myIdx, j + 3);
      int iA2 = __shfl(myIdx, j + 4), iB2 = __shfl(myIdx, j + 5);
      int iA3 = __shfl(myIdx, j + 6), iB3 = __shfl(myIdx, j + 7);
      int x0 = half ? iB0 : iA0;
      int x1 = half ? iB1 : iA1;
      int x2 = half ? iB2 : iA2;
      int x3 = half ? iB3 : iA3;
      uint2 v0 = *(const uint2*)&sU[(size_t)x0 * 64 + 2 * sl];
      uint2 v1 = *(const uint2*)&sU[(size_t)x1 * 64 + 2 * sl];
      uint2 v2 = *(const uint2*)&sU[(size_t)x2 * 64 + 2 * sl];
      uint2 v3 = *(const uint2*)&sU[(size_t)x3 * 64 + 2 * sl];
      a0 += bfLo(v0.x); a1 += bfHi(v0.x); a2 += bfLo(v0.y); a3 += bfHi(v0.y);
      a0 += bfLo(v1.x); a1 += bfHi(v1.x); a2 += bfLo(v1.y); a3 += bfHi(v1.y);
      a0 += bfLo(v2.x); a1 += bfHi(v2.x); a2 += bfLo(v2.y); a3 += bfHi(v2.y);
      a0 += bfLo(v3.x); a1 += bfHi(v3.x); a2 += bfLo(v3.y); a3 += bfHi(v3.y);
    }
    for (; j < c; j += 2) {  // pair tail (odd c and c>64)
      int iA = (j < cl) ? __shfl(myIdx, j) : es[j];
      int hasB = (j + 1 < c);
      int iB = hasB ? ((j + 1 < cl) ? __shfl(myIdx, j + 1) : es[j + 1]) : iA;
      int x = half ? iB : iA;
      uint2 v = *(const uint2*)&sU[(size_t)x * 64 + 2 * sl];
      if (half && !hasB) { v.x = 0u; v.y = 0u; }
      a0 += bfLo(v.x); a1 += bfHi(v.x); a2 += bfLo(v.y); a3 += bfHi(v.y);
    }
    a0 += __shfl_xor(a0, 32);
    a1 += __shfl_xor(a1, 32);
    a2 += __shfl_xor(a2, 32);
    a3 += __shfl_xor(a3, 32);
    if (half == 0) {  // pack & store t row (256B, 32 lanes x uint2)
      uint2 o;
      o.x = (unsigned)f2bf(dv * a0) | ((unsigned)f2bf(dv * a1) << 16);
      o.y = (unsigned)f2bf(dv * a2) | ((unsigned)f2bf(dv * a3) << 16);
      *(uint2*)&tB[(size_t)node * 64 + 2 * sl] = o;
    }
  }
}

// ---- k_gemmM: MFMA GEMM. t (bf16 rows) @ W + b -> out fp32 [+ sNext] ------
// Wave tile: 16 nodes x NFO cols; K = 128 in 4 chunks of 32.
// Wt LDS layout: [col][k] bf16, 8B granule h stored at h ^ (col&7).
template <int NFO, bool RELU, bool WRITE_S>
__global__ __launch_bounds__(256) void k_gemmM(const unsigned* __restrict__ tB,
                                               const float* __restrict__ W,
                                               const float* __restrict__ bias,
                                               const float* __restrict__ dinv,
                                               float* __restrict__ out,
                                               unsigned* __restrict__ sNext, int n) {
  __shared__ unsigned short Wt[NFO * 128];  // NFO cols x 128 k (swizzled)
  for (int t = threadIdx.x; t < 128 * NFO; t += 256) {
    int k = t / NFO, c = t % NFO;  // W row-major [k][col]
    int hs = (k >> 2) ^ (c & 7);   // 8B granule swizzle
    Wt[c * 128 + hs * 4 + (k & 3)] = f2bf(W[t]);
  }
  __syncthreads();
  const int wid = threadIdx.x >> 6, lane = threadIdx.x & 63;
  const int r16 = lane & 15;  // A-row(node) / B,C-col within tile
  const int q4 = lane >> 4;   // quarter
  const int NT = NFO / 16;
  for (int node0 = (blockIdx.x * 4 + wid) * 16; node0 < n;
       node0 += gridDim.x * 4 * 16) {
    if (node0 + 16 <= n) {
      const unsigned* trow = tB + (size_t)(node0 + r16) * 64;
      union { uint2 u2[2]; bfrag8 v; } Af[4];
      #pragma unroll
      for (int kc = 0; kc < 4; kc++) {
        Af[kc].u2[0] = *(const uint2*)&trow[kc * 16 + 2 * q4];      // k..k+3
        Af[kc].u2[1] = *(const uint2*)&trow[kc * 16 + 8 + 2 * q4];  // k+16..+19
      }
      float dvr[4];
      if (WRITE_S) {
        #pragma unroll
        for (int r = 0; r < 4; r++) dvr[r] = dinv[node0 + q4 * 4 + r];
      }
      #pragma unroll
      for (int ct = 0; ct < NT; ct++) {
        const int col = 16 * ct + r16;
        const int cbase = col * 128;
        const int csw = col & 7;
        ffrag4 acc = {0.f, 0.f, 0.f, 0.f};
        #pragma unroll
        for (int kc = 0; kc < 4; kc++) {
          int h0 = kc * 8 + q4;
          union { uint2 u2[2]; bfrag8 v; } Bf;
          Bf.u2[0] = *(const uint2*)&Wt[cbase + ((h0) ^ csw) * 4];
          Bf.u2[1] = *(const uint2*)&Wt[cbase + ((h0 + 4) ^ csw) * 4];
          acc = __builtin_amdgcn_mfma_f32_16x16x32_bf16(Af[kc].v, Bf.v, acc,
                                                        0, 0, 0);
        }
        float bb = bias[col];
        #pragma unroll
        for (int r = 0; r < 4; r++) {
          int node = node0 + q4 * 4 + r;
          float v = acc[r] + bb;
          if (RELU) v = fmaxf(v, 0.f);
          out[(size_t)node * NFO + col] = v;
          if (WRITE_S) {
            float sv = dvr[r] * v;
            float pv = __shfl_xor(sv, 1);  // partner col (col^1)
            if ((lane & 1) == 0)
              sNext[(size_t)node * 64 + (col >> 1)] =
                  (unsigned)f2bf(sv) | ((unsigned)f2bf(pv) << 16);
          }
        }
      }
    } else {
      // tail (<16 nodes): direct scalar recompute (N%16==0 here; safety only)
      for (int idx = lane; idx < 16 * NFO; idx += 64) {
        int node = node0 + idx / NFO;
        if (node < n) {
          int col = idx % NFO;
          float acc = 0.f;
          for (int k = 0; k < 128; k++) {
            unsigned tw = tB[(size_t)node * 64 + (k >> 1)];
            float tv = (k & 1) ? bfHi(tw) : bfLo(tw);
            int hs = (k >> 2) ^ (col & 7);
            unsigned short wv = Wt[col * 128 + hs * 4 + (k & 3)];
            acc = fmaf(tv, __uint_as_float(((unsigned)wv) << 16), acc);
          }
          float v = acc + bias[col];
          if (RELU) v = fmaxf(v, 0.f);
          out[(size_t)node * NFO + col] = v;
          if (WRITE_S) {
            unsigned short* sh = (unsigned short*)sNext;
            sh[(size_t)node * 128 + col] = f2bf(dinv[node] * v);
          }
        }
      }
    }
  }
}

// --------------------- fp32 fused kernel (ws-fallback) ---------------------

template <int NFO, bool RELU>
__global__ __launch_bounds__(512) void k_layer_f32(const float* __restrict__ in,
                                                   const float* __restrict__ W,
                                                   const float* __restrict__ bias,
                                                   const float* __restrict__ dinv,
                                                   const int* __restrict__ eSrc,
                                                   const int* __restrict__ rowStart,
                                                   const int* __restrict__ cnt,
                                                   float* __restrict__ out, int n) {
  __shared__ float Wl[128 * NFO];
  for (int t = threadIdx.x; t < 128 * NFO; t += 512) Wl[t] = W[t];
  __syncthreads();
  const int wid = threadIdx.x >> 6, lane = threadIdx.x & 63;
  for (int node = blockIdx.x * 8 + wid; node < n; node += gridDim.x * 8) {
    const int s = rowStart[node], c = cnt[node];
    const int* es = eSrc + s;
    const float dv = dinv[node];
    float2 x2 = *(const float2*)&in[(size_t)node * 128 + 2 * lane];
    float ax = dv * x2.x, ay = dv * x2.y;
    int j = 0;
    for (; j + 4 <= c; j += 4) {
      int s0 = es[j], s1 = es[j + 1], s2 = es[j + 2], s3 = es[j + 3];
      float d0 = dinv[s0], d1 = dinv[s1], d2 = dinv[s2], d3 = dinv[s3];
      float2 v0 = *(const float2*)&in[(size_t)s0 * 128 + 2 * lane];
      float2 v1 = *(const float2*)&in[(size_t)s1 * 128 + 2 * lane];
      float2 v2 = *(const float2*)&in[(size_t)s2 * 128 + 2 * lane];
      float2 v3 = *(const float2*)&in[(size_t)s3 * 128 + 2 * lane];
      ax = fmaf(d0, v0.x, ax); ay = fmaf(d0, v0.y, ay);
      ax = fmaf(d1, v1.x, ax); ay = fmaf(d1, v1.y, ay);
      ax = fmaf(d2, v2.x, ax); ay = fmaf(d2, v2.y, ay);
      ax = fmaf(d3, v3.x, ax); ay = fmaf(d3, v3.y, ay);
    }
    for (; j < c; j++) {
      int sj = es[j];
      float dj = dinv[sj];
      float2 v = *(const float2*)&in[(size_t)sj * 128 + 2 * lane];
      ax = fmaf(dj, v.x, ax); ay = fmaf(dj, v.y, ay);
    }
    ax *= dv; ay *= dv;
    if constexpr (NFO == 128) {
      float o0 = 0.f, o1 = 0.f;
      #pragma unroll 4
      for (int kk = 0; kk < 64; kk++) {
        float xa = __shfl(ax, kk);
        float xb = __shfl(ay, kk);
        float2 wA = *(const float2*)&Wl[(2 * kk) * 128 + 2 * lane];
        float2 wB = *(const float2*)&Wl[(2 * kk + 1) * 128 + 2 * lane];
        o0 = fmaf(xa, wA.x, o0); o1 = fmaf(xa, wA.y, o1);
        o0 = fmaf(xb, wB.x, o0); o1 = fmaf(xb, wB.y, o1);
      }
      float2 bb = *(const float2*)&bias[2 * lane];
      float r0 = o0 + bb.x, r1 = o1 + bb.y;
      if (RELU) { r0 = fmaxf(r0, 0.f); r1 = fmaxf(r1, 0.f); }
      *(float2*)&out[(size_t)node * 128 + 2 * lane] = make_float2(r0, r1);
    } else {
      float o0 = 0.f;
      #pragma unroll 4
      for (int kk = 0; kk < 64; kk++) {
        float xa = __shfl(ax, kk);
        float xb = __shfl(ay, kk);
        o0 = fmaf(xa, Wl[(2 * kk) * NFO + lane], o0);
        o0 = fmaf(xb, Wl[(2 * kk + 1) * NFO + lane], o0);
      }
      float r0 = o0 + bias[lane];
      if (RELU) r0 = fmaxf(r0, 0.f);
      out[(size_t)node * NFO + lane] = r0;
    }
  }
}

// ---------------------------------------------------------------------------

extern "C" void kernel_launch(void* const* d_in, const int* in_sizes, int n_in,
                              void* d_out, int out_size, void* d_ws, size_t ws_size,
                              hipStream_t stream) {
  const float* x  = (const float*)d_in[0];
  const int*   ei = (const int*)d_in[1];
  const float* W1 = (const float*)d_in[2];
  const float* b1 = (const float*)d_in[3];
  const float* W2 = (const float*)d_in[4];
  const float* b2 = (const float*)d_in[5];
  const float* W3 = (const float*)d_in[6];
  const float* b3 = (const float*)d_in[7];

  const int N = in_sizes[0] / 128;
  const int E = in_sizes[1] / 2;
  const int* src = ei;
  const int* dst = ei + E;

  char* ws = (char*)d_ws;
  size_t off = 0;
  auto alloc = [&](size_t bytes) -> void* {
    void* p = ws + off;
    off = (off + bytes + 255) & ~(size_t)255;
    return p;
  };
  int*   cnt      = (int*)alloc((size_t)N * 4);
  int*   fillPos  = (int*)alloc((size_t)N * 4);
  int*   rowStart = (int*)alloc((size_t)N * 4);
  float* dinv     = (float*)alloc((size_t)N * 4);
  int*   bsum     = (int*)alloc(512);
  int*   eSrc     = (int*)alloc((size_t)E * 4);
  unsigned* sU    = (unsigned*)alloc((size_t)N * 64 * 4);  // s rows, bf16, 256B
  unsigned* tB    = (unsigned*)alloc((size_t)N * 64 * 4);  // t rows, bf16, 256B
  const bool fast = (ws_size >= off);                       // ~59.2 MB

  float* y    = (float*)d_out;          // [N,64]
  float* out1 = y + (size_t)N * 64;     // [N,128]
  float* out2 = out1 + (size_t)N * 128; // [N,128]

  // ---- CSR build ----
  k_zero<<<(N + 255) / 256, 256, 0, stream>>>(cnt, fillPos, N);
  k_deg<<<2048, 256, 0, stream>>>(dst, cnt, E);
  k_dinv<<<(N + 255) / 256, 256, 0, stream>>>(cnt, dinv, N);
  int nChunks = (N + 1023) / 1024;
  k_scan1<<<nChunks, 256, 0, stream>>>(cnt, rowStart, bsum, N);
  k_scan2<<<1, 128, 0, stream>>>(bsum, nChunks);
  k_scan3<<<(N + 255) / 256, 256, 0, stream>>>(rowStart, bsum, N);
  const int rsize = (N + 7) / 8;
  k_fill8<<<2048, 256, 0, stream>>>(src, dst, rowStart, fillPos, eSrc, E, rsize);

  if (fast) {
    const int aggBlocks = (N + 3) / 4;
    const int tiles = (N + 15) / 16;
    const int gmBlocks = (tiles + 3) / 4;
    k_scale<<<(N * 16 + 255) / 256, 256, 0, stream>>>(x, dinv, (uint4*)sU, N * 16);
    // L1
    k_agg<<<aggBlocks, 256, 0, stream>>>(sU, dinv, eSrc, rowStart, cnt, tB, N);
    k_gemmM<128, true, true><<<gmBlocks, 256, 0, stream>>>(tB, W1, b1, dinv, out1, sU, N);
    // L2
    k_agg<<<aggBlocks, 256, 0, stream>>>(sU, dinv, eSrc, rowStart, cnt, tB, N);
    k_gemmM<128, true, true><<<gmBlocks, 256, 0, stream>>>(tB, W2, b2, dinv, out2, sU, N);
    // L3
    k_agg<<<aggBlocks, 256, 0, stream>>>(sU, dinv, eSrc, rowStart, cnt, tB, N);
    k_gemmM<64, false, false><<<gmBlocks, 256, 0, stream>>>(tB, W3, b3, dinv, y, nullptr, N);
  } else {
    k_layer_f32<128, true ><<<1024, 512, 0, stream>>>(x,    W1, b1, dinv, eSrc, rowStart, cnt, out1, N);
    k_layer_f32<128, true ><<<1024, 512, 0, stream>>>(out1, W2, b2, dinv, eSrc, rowStart, cnt, out2, N);
    k_layer_f32<64,  false><<<1024, 512, 0, stream>>>(out2, W3, b3, dinv, eSrc, rowStart, cnt, y,    N);
  }
}